// Round 1
// baseline (1490.834 us; speedup 1.0000x reference)
//
#include <hip/hip_runtime.h>
#include <hip/hip_bf16.h>

// ---------------------------------------------------------------------------
// ERCGNN: GAT(2 layers, 8 heads) + 3x GCN(2 layers) + self MLP, BN everywhere,
// concat -> linear classifier. Fully fp32, CSR-gather aggregation (no float
// atomics in hot path), classifier accumulated per-branch into d_out.
// ---------------------------------------------------------------------------

#define NN 50000
#define NE 500000
#define DD 128
#define NH 8
#define DHD 16
#define NCLS 7

// ---------------- CSR build ----------------

__global__ void count_kernel(const int* __restrict__ row, int* __restrict__ cnt) {
    int e = blockIdx.x * 256 + threadIdx.x;
    if (e < NE) atomicAdd(&cnt[row[e]], 1);
}

__global__ __launch_bounds__(1024) void scan_kernel(const int* __restrict__ cnt,
                                                    int* __restrict__ row_ptr,
                                                    int* __restrict__ fill) {
    __shared__ int sums[1024];
    int t = threadIdx.x;
    const int CH = 49;  // ceil(50000/1024)
    int base = t * CH;
    int s = 0;
    for (int i = 0; i < CH; ++i) {
        int idx = base + i;
        s += (idx < NN) ? cnt[idx] : 0;
    }
    sums[t] = s;
    __syncthreads();
    for (int off = 1; off < 1024; off <<= 1) {
        int v = (t >= off) ? sums[t - off] : 0;
        __syncthreads();
        sums[t] += v;
        __syncthreads();
    }
    int run = (t == 0) ? 0 : sums[t - 1];
    for (int i = 0; i < CH; ++i) {
        int idx = base + i;
        if (idx < NN) {
            row_ptr[idx] = run;
            fill[idx] = run;
            run += cnt[idx];
        }
    }
    if (t == 1023) row_ptr[NN] = sums[1023];
}

__global__ void scatter_kernel(const int* __restrict__ row, const int* __restrict__ col,
                               const float* __restrict__ vg, const float* __restrict__ vu,
                               const float* __restrict__ vp, const float* __restrict__ vf,
                               int* __restrict__ fill, int* __restrict__ col_s,
                               float* __restrict__ vgs, float* __restrict__ vus,
                               float* __restrict__ vps, float* __restrict__ vfs) {
    int e = blockIdx.x * 256 + threadIdx.x;
    if (e >= NE) return;
    int r = row[e];
    int pos = atomicAdd(&fill[r], 1);
    col_s[pos] = col[e];
    vgs[pos] = vg[e];
    vus[pos] = vu[e];
    vps[pos] = vp[e];
    vfs[pos] = vf[e];
}

// ---------------- dense matmul C[N,128] = A[N,128] @ W[128,128] + b ----------------
// Block: 256 threads, 64 rows. A tile staged in LDS (32KB), W streamed from L2.

template <bool RELU>
__global__ __launch_bounds__(256) void matmul_kernel(const float* __restrict__ A,
                                                     const float* __restrict__ W,
                                                     const float* __restrict__ bias,
                                                     float* __restrict__ C, int nrows) {
    __shared__ float As[64][DD];
    int t = threadIdx.x;
    int r0 = blockIdx.x * 64;
    {
        const float4* A4 = (const float4*)(A + (size_t)r0 * DD);
        float4* S4 = (float4*)&As[0][0];
        for (int i = t; i < 64 * DD / 4; i += 256) {
            int row = r0 + (i >> 5);
            S4[i] = (row < nrows) ? A4[i] : make_float4(0.f, 0.f, 0.f, 0.f);
        }
    }
    __syncthreads();
    int tx = t & 31, ty = t >> 5;
    float acc[8][4] = {};
    for (int k = 0; k < DD; k += 4) {
        float4 a4[8];
#pragma unroll
        for (int r = 0; r < 8; ++r) a4[r] = *(const float4*)&As[ty * 8 + r][k];
#pragma unroll
        for (int kk = 0; kk < 4; ++kk) {
            float4 w = *(const float4*)&W[(size_t)(k + kk) * DD + tx * 4];
#pragma unroll
            for (int r = 0; r < 8; ++r) {
                float a = ((const float*)&a4[r])[kk];
                acc[r][0] += a * w.x;
                acc[r][1] += a * w.y;
                acc[r][2] += a * w.z;
                acc[r][3] += a * w.w;
            }
        }
    }
    float4 b4 = *(const float4*)&bias[tx * 4];
#pragma unroll
    for (int r = 0; r < 8; ++r) {
        int row = r0 + ty * 8 + r;
        if (row < nrows) {
            float4 o;
            o.x = acc[r][0] + b4.x;
            o.y = acc[r][1] + b4.y;
            o.z = acc[r][2] + b4.z;
            o.w = acc[r][3] + b4.w;
            if (RELU) {
                o.x = fmaxf(o.x, 0.f);
                o.y = fmaxf(o.y, 0.f);
                o.z = fmaxf(o.z, 0.f);
                o.w = fmaxf(o.w, 0.f);
            }
            *(float4*)&C[(size_t)row * DD + tx * 4] = o;
        }
    }
}

// ---------------- GAT attention scalars (leaky relu applied here) ----------------

__global__ void att_kernel(const float* __restrict__ hs, const float* __restrict__ a_s,
                           const float* __restrict__ a_n, float* __restrict__ ats,
                           float* __restrict__ atn) {
    int idx = blockIdx.x * 256 + threadIdx.x;  // n*8 + h
    if (idx >= NN * NH) return;
    int h = idx & 7;
    int n = idx >> 3;
    const float* hp = hs + (size_t)n * DD + h * DHD;
    const float* asp = a_s + h * DHD;
    const float* anp = a_n + h * DHD;
    float ds = 0.f, dn = 0.f;
#pragma unroll
    for (int k = 0; k < DHD; ++k) {
        float v = hp[k];
        ds += v * asp[k];
        dn += v * anp[k];
    }
    ats[idx] = ds > 0.f ? ds : 0.2f * ds;
    atn[idx] = dn > 0.f ? dn : 0.2f * dn;
}

// ---------------- SpMM (wave per row, float2 per lane) ----------------

__global__ __launch_bounds__(256) void spmm_gcn_kernel(const float* __restrict__ h,
                                                       const int* __restrict__ row_ptr,
                                                       const int* __restrict__ col_s,
                                                       const float* __restrict__ val_s,
                                                       float* __restrict__ agg) {
    int r = (blockIdx.x * 256 + threadIdx.x) >> 6;
    int lane = threadIdx.x & 63;
    if (r >= NN) return;
    int start = row_ptr[r], end = row_ptr[r + 1];
    float2 acc = make_float2(0.f, 0.f);
    for (int j = start; j < end; ++j) {
        int c = col_s[j];
        float w = val_s[j];
        float2 hv = *(const float2*)&h[(size_t)c * DD + lane * 2];
        acc.x += w * hv.x;
        acc.y += w * hv.y;
    }
    *(float2*)&agg[(size_t)r * DD + lane * 2] = acc;
}

__global__ __launch_bounds__(256) void spmm_gat_kernel(
    const float* __restrict__ hn, const float* __restrict__ ats, const float* __restrict__ atn,
    const int* __restrict__ row_ptr, const int* __restrict__ col_s,
    const float* __restrict__ val_s, float* __restrict__ agg) {
    int r = (blockIdx.x * 256 + threadIdx.x) >> 6;
    int lane = threadIdx.x & 63;
    if (r >= NN) return;
    int hh = lane >> 3;  // head of features 2*lane, 2*lane+1
    float a_s = ats[r * NH + hh];
    int start = row_ptr[r], end = row_ptr[r + 1];
    float2 acc = make_float2(0.f, 0.f);
    for (int j = start; j < end; ++j) {
        int c = col_s[j];
        float v = val_s[j];
        float e = (a_s + atn[c * NH + hh]) * v;
        float2 hv = *(const float2*)&hn[(size_t)c * DD + lane * 2];
        acc.x += e * hv.x;
        acc.y += e * hv.y;
    }
    *(float2*)&agg[(size_t)r * DD + lane * 2] = acc;
}

// ---------------- BatchNorm (train mode, gamma=1, beta=0, eps=1e-9) ----------------

template <bool RELU_IN>
__global__ __launch_bounds__(256) void bn_stats_kernel(const float* __restrict__ x,
                                                       float* __restrict__ stats) {
    int c = threadIdx.x & 127;
    int sub = threadIdx.x >> 7;
    int rows_per_block = (NN + gridDim.x - 1) / gridDim.x;
    int rbeg = blockIdx.x * rows_per_block;
    int rend = min(rbeg + rows_per_block, NN);
    float s = 0.f, q = 0.f;
    for (int r = rbeg + sub; r < rend; r += 2) {
        float v = x[(size_t)r * DD + c];
        if (RELU_IN) v = fmaxf(v, 0.f);
        s += v;
        q += v * v;
    }
    atomicAdd(&stats[c], s);
    atomicAdd(&stats[DD + c], q);
}

template <bool RELU_IN>
__global__ void bn_apply_kernel(float* __restrict__ x, const float* __restrict__ stats) {
    int idx = blockIdx.x * 256 + threadIdx.x;  // float4 index
    if (idx >= NN * (DD / 4)) return;
    int c0 = (idx & 31) * 4;
    const float inv_n = 1.0f / (float)NN;
    float4 v = ((const float4*)x)[idx];
    float* vp = (float*)&v;
#pragma unroll
    for (int i = 0; i < 4; ++i) {
        int c = c0 + i;
        float m = stats[c] * inv_n;
        float var = stats[DD + c] * inv_n - m * m;
        float scale = rsqrtf(var + 1e-9f);
        float val = vp[i];
        if (RELU_IN) val = fmaxf(val, 0.f);
        vp[i] = (val - m) * scale;
    }
    ((float4*)x)[idx] = v;
}

// ---------------- classifier ----------------

__global__ void cls_init_kernel(const float* __restrict__ b_cls, float* __restrict__ out) {
    int idx = blockIdx.x * 256 + threadIdx.x;
    if (idx < NN * NCLS) out[idx] = b_cls[idx % NCLS];
}

__global__ __launch_bounds__(256) void cls_acc_kernel(const float* __restrict__ o,
                                                      const float* __restrict__ Wc,
                                                      float* __restrict__ out) {
    __shared__ float Wl[DD * NCLS];
    int t = threadIdx.x;
    for (int i = t; i < DD * NCLS; i += 256) Wl[i] = Wc[i];
    __syncthreads();
    int n = blockIdx.x * 256 + t;
    if (n >= NN) return;
    float acc[NCLS] = {};
    const float4* orow = (const float4*)(o + (size_t)n * DD);
    for (int k4 = 0; k4 < DD / 4; ++k4) {
        float4 v = orow[k4];
#pragma unroll
        for (int kk = 0; kk < 4; ++kk) {
            float a = ((const float*)&v)[kk];
            int k = k4 * 4 + kk;
#pragma unroll
            for (int c = 0; c < NCLS; ++c) acc[c] += a * Wl[k * NCLS + c];
        }
    }
#pragma unroll
    for (int c = 0; c < NCLS; ++c) out[n * NCLS + c] += acc[c];
}

// ---------------- GAT weight repack [H,DIN,DH] -> [DIN, H*DH] ----------------

__global__ void repack_gat_kernel(const float* __restrict__ w, float* __restrict__ out) {
    int idx = blockIdx.x * 256 + threadIdx.x;
    if (idx >= DD * DD) return;
    int k = idx >> 7;   // input dim
    int c = idx & 127;  // h*16+kk
    int h = c >> 4, kk = c & 15;
    out[idx] = w[(size_t)(h * DD + k) * DHD + kk];
}

// ---------------------------------------------------------------------------

extern "C" void kernel_launch(void* const* d_in, const int* in_sizes, int n_in, void* d_out,
                              int out_size, void* d_ws, size_t ws_size, hipStream_t stream) {
    const float* f_in = (const float*)d_in[0];
    const int* edge_row = (const int*)d_in[1];
    const int* edge_col = (const int*)d_in[2];
    const float* vals_gat = (const float*)d_in[3];
    const float* vals_uttr = (const float*)d_in[4];
    const float* vals_past = (const float*)d_in[5];
    const float* vals_futr = (const float*)d_in[6];
    const float* gat_Ws = (const float*)d_in[7];
    const float* gat_bs = (const float*)d_in[8];
    const float* gat_Wn = (const float*)d_in[9];
    const float* gat_bn = (const float*)d_in[10];
    const float* gat_as = (const float*)d_in[11];
    const float* gat_an = (const float*)d_in[12];
    const float* W_uttr = (const float*)d_in[13];
    const float* b_uttr = (const float*)d_in[14];
    const float* W_past = (const float*)d_in[15];
    const float* b_past = (const float*)d_in[16];
    const float* W_futr = (const float*)d_in[17];
    const float* b_futr = (const float*)d_in[18];
    const float* W_self = (const float*)d_in[19];
    const float* b_self = (const float*)d_in[20];
    const float* W_cls = (const float*)d_in[21];
    const float* b_cls = (const float*)d_in[22];
    float* out = (float*)d_out;

    // workspace carve-up (256B aligned)
    char* ws = (char*)d_ws;
    size_t off = 0;
    auto alloc = [&](size_t bytes) -> void* {
        void* p = ws + off;
        off = (off + bytes + 255) & ~(size_t)255;
        return p;
    };
    float* bufA = (float*)alloc((size_t)NN * DD * 4);
    float* tmp1 = (float*)alloc((size_t)NN * DD * 4);
    float* tmp2 = (float*)alloc((size_t)NN * DD * 4);
    float* ats_b = (float*)alloc((size_t)NN * NH * 4);
    float* atn_b = (float*)alloc((size_t)NN * NH * 4);
    float* Wg1 = (float*)alloc(DD * DD * 4);
    float* Wg2 = (float*)alloc(DD * DD * 4);
    float* stats = (float*)alloc(2 * DD * 4);
    int* cnt = (int*)alloc((size_t)NN * 4);
    int* row_ptr = (int*)alloc((size_t)(NN + 1) * 4);
    int* fill = (int*)alloc((size_t)NN * 4);
    int* col_s = (int*)alloc((size_t)NE * 4);
    float* vgs = (float*)alloc((size_t)NE * 4);
    float* vus = (float*)alloc((size_t)NE * 4);
    float* vps = (float*)alloc((size_t)NE * 4);
    float* vfs = (float*)alloc((size_t)NE * 4);

    const int gE = (NE + 255) / 256;        // 1954
    const int gMM = (NN + 63) / 64;         // 782
    const int gATT = (NN * NH + 255) / 256; // 1563
    const int gSP = (NN + 3) / 4;           // 12500
    const int gBN = (NN * (DD / 4) + 255) / 256;  // 6250
    const int gCI = (NN * NCLS + 255) / 256;
    const int gCA = (NN + 255) / 256;

    // ---- CSR build (shared by all branches) ----
    hipMemsetAsync(cnt, 0, (size_t)NN * 4, stream);
    count_kernel<<<gE, 256, 0, stream>>>(edge_row, cnt);
    scan_kernel<<<1, 1024, 0, stream>>>(cnt, row_ptr, fill);
    scatter_kernel<<<gE, 256, 0, stream>>>(edge_row, edge_col, vals_gat, vals_uttr, vals_past,
                                           vals_futr, fill, col_s, vgs, vus, vps, vfs);

    cls_init_kernel<<<gCI, 256, 0, stream>>>(b_cls, out);

    // ---- GAT branch ----
    for (int l = 0; l < 2; ++l) {
        repack_gat_kernel<<<64, 256, 0, stream>>>(gat_Ws + (size_t)l * DD * DD, Wg1);
        repack_gat_kernel<<<64, 256, 0, stream>>>(gat_Wn + (size_t)l * DD * DD, Wg2);
        const float* fl = (l == 0) ? f_in : bufA;
        matmul_kernel<true><<<gMM, 256, 0, stream>>>(fl, Wg1, gat_bs + l * DD, tmp1, NN);
        matmul_kernel<true><<<gMM, 256, 0, stream>>>(fl, Wg2, gat_bn + l * DD, tmp2, NN);
        att_kernel<<<gATT, 256, 0, stream>>>(tmp1, gat_as + l * DD, gat_an + l * DD, ats_b, atn_b);
        spmm_gat_kernel<<<gSP, 256, 0, stream>>>(tmp2, ats_b, atn_b, row_ptr, col_s, vgs, bufA);
        hipMemsetAsync(stats, 0, 2 * DD * 4, stream);
        bn_stats_kernel<false><<<256, 256, 0, stream>>>(bufA, stats);
        bn_apply_kernel<false><<<gBN, 256, 0, stream>>>(bufA, stats);
    }
    cls_acc_kernel<<<gCA, 256, 0, stream>>>(bufA, W_cls + 0 * NCLS, out);

    // ---- GCN branches ----
    const float* Wb[3] = {W_uttr, W_past, W_futr};
    const float* bb[3] = {b_uttr, b_past, b_futr};
    const float* vb[3] = {vus, vps, vfs};
    for (int br = 0; br < 3; ++br) {
        for (int l = 0; l < 2; ++l) {
            const float* fl = (l == 0) ? f_in : bufA;
            matmul_kernel<false><<<gMM, 256, 0, stream>>>(fl, Wb[br] + (size_t)l * DD * DD,
                                                          bb[br] + l * DD, tmp1, NN);
            spmm_gcn_kernel<<<gSP, 256, 0, stream>>>(tmp1, row_ptr, col_s, vb[br], bufA);
            hipMemsetAsync(stats, 0, 2 * DD * 4, stream);
            bn_stats_kernel<true><<<256, 256, 0, stream>>>(bufA, stats);
            bn_apply_kernel<true><<<gBN, 256, 0, stream>>>(bufA, stats);
        }
        cls_acc_kernel<<<gCA, 256, 0, stream>>>(bufA, W_cls + (size_t)(128 + 128 * br) * NCLS, out);
    }

    // ---- self branch ----
    matmul_kernel<true><<<gMM, 256, 0, stream>>>(f_in, W_self, b_self, tmp1, NN);
    hipMemsetAsync(stats, 0, 2 * DD * 4, stream);
    bn_stats_kernel<false><<<256, 256, 0, stream>>>(tmp1, stats);
    bn_apply_kernel<false><<<gBN, 256, 0, stream>>>(tmp1, stats);
    cls_acc_kernel<<<gCA, 256, 0, stream>>>(tmp1, W_cls + (size_t)512 * NCLS, out);
}

// Round 2
// 1128.221 us; speedup vs baseline: 1.3214x; 1.3214x over previous
//
#include <hip/hip_runtime.h>
#include <hip/hip_bf16.h>

// ---------------------------------------------------------------------------
// ERCGNN: GAT(2L,8H) + 3x GCN(2L) + self MLP, BN(train), concat->classifier.
// R2: parallel scan, bf16 MFMA matmuls (16x16x32), BN-apply fused into
// consumers, classifier accumulates per-branch into d_out.
// ---------------------------------------------------------------------------

#define NN 50000
#define NE 500000
#define DD 128
#define NH 8
#define DHD 16
#define NCLS 7
#define SCAN_B 196  // ceil(NN/256)

typedef __attribute__((ext_vector_type(8))) short short8;
typedef __attribute__((ext_vector_type(4))) float f32x4;

__device__ __forceinline__ unsigned short f2bf(float x) {
    unsigned int u = __float_as_uint(x);
    unsigned int r = (u + 0x7fffu + ((u >> 16) & 1u)) >> 16;  // RNE
    return (unsigned short)r;
}

// ---------------- CSR build ----------------

__global__ void count_kernel(const int* __restrict__ row, int* __restrict__ cnt) {
    int e = blockIdx.x * 256 + threadIdx.x;
    if (e < NE) atomicAdd(&cnt[row[e]], 1);
}

__global__ __launch_bounds__(256) void scan1_kernel(const int* __restrict__ cnt,
                                                    int* __restrict__ pre,
                                                    int* __restrict__ bsum) {
    __shared__ int s[256];
    int t = threadIdx.x;
    int i = blockIdx.x * 256 + t;
    int v = (i < NN) ? cnt[i] : 0;
    s[t] = v;
    __syncthreads();
    for (int off = 1; off < 256; off <<= 1) {
        int u = (t >= off) ? s[t - off] : 0;
        __syncthreads();
        s[t] += u;
        __syncthreads();
    }
    if (i < NN) pre[i] = s[t] - v;  // exclusive within block
    if (t == 255) bsum[blockIdx.x] = s[255];
}

__global__ __launch_bounds__(256) void scan2_kernel(const int* __restrict__ bsum,
                                                    int* __restrict__ boff) {
    __shared__ int s[256];
    int t = threadIdx.x;
    int v = (t < SCAN_B) ? bsum[t] : 0;
    s[t] = v;
    __syncthreads();
    for (int off = 1; off < 256; off <<= 1) {
        int u = (t >= off) ? s[t - off] : 0;
        __syncthreads();
        s[t] += u;
        __syncthreads();
    }
    boff[t] = s[t] - v;  // exclusive
    if (t == 255) boff[256] = s[255];
}

__global__ __launch_bounds__(256) void scan3_kernel(const int* __restrict__ pre,
                                                    const int* __restrict__ boff,
                                                    int* __restrict__ row_ptr,
                                                    int* __restrict__ fill) {
    int t = threadIdx.x;
    int i = blockIdx.x * 256 + t;
    if (i < NN) {
        int v = pre[i] + boff[blockIdx.x];
        row_ptr[i] = v;
        fill[i] = v;
    }
    if (blockIdx.x == 0 && t == 0) row_ptr[NN] = boff[256];
}

__global__ void scatter_kernel(const int* __restrict__ row, const int* __restrict__ col,
                               const float* __restrict__ vg, const float* __restrict__ vu,
                               const float* __restrict__ vp, const float* __restrict__ vf,
                               int* __restrict__ fill, int* __restrict__ col_s,
                               float* __restrict__ vgs, float* __restrict__ vus,
                               float* __restrict__ vps, float* __restrict__ vfs) {
    int e = blockIdx.x * 256 + threadIdx.x;
    if (e >= NE) return;
    int r = row[e];
    int pos = atomicAdd(&fill[r], 1);
    col_s[pos] = col[e];
    vgs[pos] = vg[e];
    vus[pos] = vu[e];
    vps[pos] = vp[e];
    vfs[pos] = vf[e];
}

// ---------------- weight prep: 11x [128][128] fp32 -> col-major bf16 ----------------
// Wt[w][n][k] = W_logical[k][n].  First 4 are GAT ([H,128,16] layout).

struct WPrepArgs {
    const float* src[11];
};

__global__ __launch_bounds__(256) void wprep_kernel(WPrepArgs a, short* __restrict__ out) {
    int idx = blockIdx.x * 256 + threadIdx.x;
    if (idx >= 11 * DD * DD) return;
    int w = idx >> 14;
    int r = idx & 16383;
    int n = r >> 7, k = r & 127;
    const float* W = a.src[w];
    float v = (w < 4) ? W[(size_t)((n >> 4) * DD + k) * DHD + (n & 15)]
                      : W[(size_t)k * DD + n];
    out[idx] = (short)f2bf(v);
}

// ---------------- MFMA matmul: C[N,128] = pre(A)[N,128] @ W[128,128] + b ----------
// PRE: 0 none, 1 batchnorm, 2 relu+batchnorm. Block = 256 thr = 4 waves, 64 rows.

template <int PRE, bool RELU_OUT>
__global__ __launch_bounds__(256) void mfma_mm(const float* __restrict__ A,
                                               const short* __restrict__ Wt,
                                               const float* __restrict__ bias,
                                               const float* __restrict__ stats,
                                               float* __restrict__ C) {
    __shared__ short As[64 * DD];
    __shared__ float mS[DD], sS[DD];
    int t = threadIdx.x;
    int r0 = blockIdx.x * 64;

    if (PRE) {
        if (t < DD) {
            const float inv_n = 1.0f / (float)NN;
            float m = stats[t] * inv_n;
            float var = stats[DD + t] * inv_n - m * m;
            mS[t] = m;
            sS[t] = rsqrtf(var + 1e-9f);
        }
        __syncthreads();
    }

    // stage A tile (64x128) fp32 -> bf16, XOR-swizzled on 16B units
    {
        int srow = t >> 2;
        int sk0 = (t & 3) * 32;
        int grow = r0 + srow;
        const float* Ar = A + (size_t)grow * DD;
#pragma unroll
        for (int j = 0; j < 4; ++j) {
            int k0 = sk0 + j * 8;
            short8 frag = {0, 0, 0, 0, 0, 0, 0, 0};
            if (grow < NN) {
                float4 v0 = *(const float4*)(Ar + k0);
                float4 v1 = *(const float4*)(Ar + k0 + 4);
                float vv[8] = {v0.x, v0.y, v0.z, v0.w, v1.x, v1.y, v1.z, v1.w};
#pragma unroll
                for (int e = 0; e < 8; ++e) {
                    float x = vv[e];
                    if (PRE == 2) x = fmaxf(x, 0.f);
                    if (PRE) x = (x - mS[k0 + e]) * sS[k0 + e];
                    frag[e] = (short)f2bf(x);
                }
            }
            int byte = srow * 256 + k0 * 2;
            byte ^= (srow & 7) << 4;
            *(short8*)((char*)As + byte) = frag;
        }
    }
    __syncthreads();

    int w = t >> 6, l = t & 63;
    int c0 = w * 32;
    int lr = l & 15, lg = l >> 4;
    f32x4 acc[4][2] = {};

#pragma unroll
    for (int s = 0; s < 4; ++s) {  // K-steps of 32
        short8 af[4];
#pragma unroll
        for (int f = 0; f < 4; ++f) {
            int rr = f * 16 + lr;
            int byte = rr * 256 + (s * 32 + lg * 8) * 2;
            byte ^= (rr & 7) << 4;
            af[f] = *(const short8*)((const char*)As + byte);
        }
#pragma unroll
        for (int g = 0; g < 2; ++g) {
            int col = c0 + g * 16 + lr;
            short8 bf = *(const short8*)&Wt[(size_t)col * DD + s * 32 + lg * 8];
#pragma unroll
            for (int f = 0; f < 4; ++f)
                acc[f][g] = __builtin_amdgcn_mfma_f32_16x16x32_bf16(af[f], bf, acc[f][g], 0, 0, 0);
        }
    }

    // epilogue: C/D layout col=lane&15, row=(lane>>4)*4+reg  [m89-verified]
#pragma unroll
    for (int f = 0; f < 4; ++f) {
        int row = r0 + f * 16 + lg * 4;
#pragma unroll
        for (int g = 0; g < 2; ++g) {
            int col = c0 + g * 16 + lr;
            float b = bias[col];
#pragma unroll
            for (int i = 0; i < 4; ++i) {
                if (row + i < NN) {
                    float o = acc[f][g][i] + b;
                    if (RELU_OUT) o = fmaxf(o, 0.f);
                    C[(size_t)(row + i) * DD + col] = o;
                }
            }
        }
    }
}

// ---------------- GAT attention scalars ----------------

__global__ void att_kernel(const float* __restrict__ hs, const float* __restrict__ a_s,
                           const float* __restrict__ a_n, float* __restrict__ ats,
                           float* __restrict__ atn) {
    int idx = blockIdx.x * 256 + threadIdx.x;  // n*8 + h
    if (idx >= NN * NH) return;
    int h = idx & 7;
    int n = idx >> 3;
    const float* hp = hs + (size_t)n * DD + h * DHD;
    const float* asp = a_s + h * DHD;
    const float* anp = a_n + h * DHD;
    float ds = 0.f, dn = 0.f;
#pragma unroll
    for (int k = 0; k < DHD; ++k) {
        float v = hp[k];
        ds += v * asp[k];
        dn += v * anp[k];
    }
    ats[idx] = ds > 0.f ? ds : 0.2f * ds;
    atn[idx] = dn > 0.f ? dn : 0.2f * dn;
}

// ---------------- SpMM (wave per row) ----------------

__global__ __launch_bounds__(256) void spmm_gcn_kernel(const float* __restrict__ h,
                                                       const int* __restrict__ row_ptr,
                                                       const int* __restrict__ col_s,
                                                       const float* __restrict__ val_s,
                                                       float* __restrict__ agg) {
    int r = (blockIdx.x * 256 + threadIdx.x) >> 6;
    int lane = threadIdx.x & 63;
    if (r >= NN) return;
    int start = row_ptr[r], end = row_ptr[r + 1];
    float2 acc = make_float2(0.f, 0.f);
    for (int j = start; j < end; ++j) {
        int c = col_s[j];
        float w = val_s[j];
        float2 hv = *(const float2*)&h[(size_t)c * DD + lane * 2];
        acc.x += w * hv.x;
        acc.y += w * hv.y;
    }
    *(float2*)&agg[(size_t)r * DD + lane * 2] = acc;
}

__global__ __launch_bounds__(256) void spmm_gat_kernel(
    const float* __restrict__ hn, const float* __restrict__ ats, const float* __restrict__ atn,
    const int* __restrict__ row_ptr, const int* __restrict__ col_s,
    const float* __restrict__ val_s, float* __restrict__ agg) {
    int r = (blockIdx.x * 256 + threadIdx.x) >> 6;
    int lane = threadIdx.x & 63;
    if (r >= NN) return;
    int hh = lane >> 3;
    float a_s = ats[r * NH + hh];
    int start = row_ptr[r], end = row_ptr[r + 1];
    float2 acc = make_float2(0.f, 0.f);
    for (int j = start; j < end; ++j) {
        int c = col_s[j];
        float v = val_s[j];
        float e = (a_s + atn[c * NH + hh]) * v;
        float2 hv = *(const float2*)&hn[(size_t)c * DD + lane * 2];
        acc.x += e * hv.x;
        acc.y += e * hv.y;
    }
    *(float2*)&agg[(size_t)r * DD + lane * 2] = acc;
}

// ---------------- BN stats (sum, sumsq per column) ----------------

template <bool RELU_IN>
__global__ __launch_bounds__(256) void bn_stats_kernel(const float* __restrict__ x,
                                                       float* __restrict__ stats) {
    int c = threadIdx.x & 127;
    int sub = threadIdx.x >> 7;
    int rows_per_block = (NN + gridDim.x - 1) / gridDim.x;
    int rbeg = blockIdx.x * rows_per_block;
    int rend = min(rbeg + rows_per_block, NN);
    float s = 0.f, q = 0.f;
    for (int r = rbeg + sub; r < rend; r += 2) {
        float v = x[(size_t)r * DD + c];
        if (RELU_IN) v = fmaxf(v, 0.f);
        s += v;
        q += v * v;
    }
    atomicAdd(&stats[c], s);
    atomicAdd(&stats[DD + c], q);
}

// ---------------- classifier: out (+)= pre(o) @ Wc_slice (+ b first time) -------

template <int PRE, bool FIRST>
__global__ __launch_bounds__(256) void cls_acc_kernel(const float* __restrict__ o,
                                                      const float* __restrict__ Wc,
                                                      const float* __restrict__ stats,
                                                      const float* __restrict__ b_cls,
                                                      float* __restrict__ out) {
    __shared__ float Wl[DD * NCLS];
    __shared__ float mS[DD], sS[DD];
    int t = threadIdx.x;
    for (int i = t; i < DD * NCLS; i += 256) Wl[i] = Wc[i];
    if (PRE && t < DD) {
        const float inv_n = 1.0f / (float)NN;
        float m = stats[t] * inv_n;
        float var = stats[DD + t] * inv_n - m * m;
        mS[t] = m;
        sS[t] = rsqrtf(var + 1e-9f);
    }
    __syncthreads();
    int n = blockIdx.x * 256 + t;
    if (n >= NN) return;
    float acc[NCLS] = {};
    const float4* orow = (const float4*)(o + (size_t)n * DD);
    for (int k4 = 0; k4 < DD / 4; ++k4) {
        float4 v = orow[k4];
#pragma unroll
        for (int kk = 0; kk < 4; ++kk) {
            int k = k4 * 4 + kk;
            float a = ((const float*)&v)[kk];
            if (PRE == 2) a = fmaxf(a, 0.f);
            if (PRE) a = (a - mS[k]) * sS[k];
#pragma unroll
            for (int c = 0; c < NCLS; ++c) acc[c] += a * Wl[k * NCLS + c];
        }
    }
#pragma unroll
    for (int c = 0; c < NCLS; ++c) {
        if (FIRST)
            out[n * NCLS + c] = acc[c] + b_cls[c];
        else
            out[n * NCLS + c] += acc[c];
    }
}

// ---------------------------------------------------------------------------

extern "C" void kernel_launch(void* const* d_in, const int* in_sizes, int n_in, void* d_out,
                              int out_size, void* d_ws, size_t ws_size, hipStream_t stream) {
    const float* f_in = (const float*)d_in[0];
    const int* edge_row = (const int*)d_in[1];
    const int* edge_col = (const int*)d_in[2];
    const float* vals_gat = (const float*)d_in[3];
    const float* vals_uttr = (const float*)d_in[4];
    const float* vals_past = (const float*)d_in[5];
    const float* vals_futr = (const float*)d_in[6];
    const float* gat_Ws = (const float*)d_in[7];
    const float* gat_bs = (const float*)d_in[8];
    const float* gat_Wn = (const float*)d_in[9];
    const float* gat_bn = (const float*)d_in[10];
    const float* gat_as = (const float*)d_in[11];
    const float* gat_an = (const float*)d_in[12];
    const float* W_uttr = (const float*)d_in[13];
    const float* b_uttr = (const float*)d_in[14];
    const float* W_past = (const float*)d_in[15];
    const float* b_past = (const float*)d_in[16];
    const float* W_futr = (const float*)d_in[17];
    const float* b_futr = (const float*)d_in[18];
    const float* W_self = (const float*)d_in[19];
    const float* b_self = (const float*)d_in[20];
    const float* W_cls = (const float*)d_in[21];
    const float* b_cls = (const float*)d_in[22];
    float* out = (float*)d_out;

    char* ws = (char*)d_ws;
    size_t off = 0;
    auto alloc = [&](size_t bytes) -> void* {
        void* p = ws + off;
        off = (off + bytes + 255) & ~(size_t)255;
        return p;
    };
    // stats_all + cnt adjacent -> single memset
    float* stats_all = (float*)alloc(9 * 2 * DD * 4);  // 9 slices of 256 floats
    int* cnt = (int*)alloc((size_t)NN * 4);
    float* bufA = (float*)alloc((size_t)NN * DD * 4);
    float* tmp1 = (float*)alloc((size_t)NN * DD * 4);
    float* tmp2 = (float*)alloc((size_t)NN * DD * 4);
    float* ats_b = (float*)alloc((size_t)NN * NH * 4);
    float* atn_b = (float*)alloc((size_t)NN * NH * 4);
    short* Wt_all = (short*)alloc((size_t)11 * DD * DD * 2);
    int* row_ptr = (int*)alloc((size_t)(NN + 1) * 4);
    int* fill = (int*)alloc((size_t)NN * 4);
    int* pre_b = (int*)alloc((size_t)NN * 4);
    int* bsum = (int*)alloc((size_t)SCAN_B * 4);
    int* boff = (int*)alloc((size_t)257 * 4);
    int* col_s = (int*)alloc((size_t)NE * 4);
    float* vgs = (float*)alloc((size_t)NE * 4);
    float* vus = (float*)alloc((size_t)NE * 4);
    float* vps = (float*)alloc((size_t)NE * 4);
    float* vfs = (float*)alloc((size_t)NE * 4);

    auto stats = [&](int s) { return stats_all + (size_t)s * 2 * DD; };
    auto Wt = [&](int w) { return Wt_all + (size_t)w * DD * DD; };

    const int gE = (NE + 255) / 256;
    const int gMM = (NN + 63) / 64;
    const int gATT = (NN * NH + 255) / 256;
    const int gSP = (NN + 3) / 4;
    const int gCA = (NN + 255) / 256;

    hipMemsetAsync(stats_all, 0, 9 * 2 * DD * 4 + (size_t)NN * 4, stream);

    // CSR build
    count_kernel<<<gE, 256, 0, stream>>>(edge_row, cnt);
    scan1_kernel<<<SCAN_B, 256, 0, stream>>>(cnt, pre_b, bsum);
    scan2_kernel<<<1, 256, 0, stream>>>(bsum, boff);
    scan3_kernel<<<SCAN_B, 256, 0, stream>>>(pre_b, boff, row_ptr, fill);
    scatter_kernel<<<gE, 256, 0, stream>>>(edge_row, edge_col, vals_gat, vals_uttr, vals_past,
                                           vals_futr, fill, col_s, vgs, vus, vps, vfs);

    // weight prep (11 matrices -> col-major bf16)
    WPrepArgs wa;
    wa.src[0] = gat_Ws;
    wa.src[1] = gat_Wn;
    wa.src[2] = gat_Ws + (size_t)DD * DD;
    wa.src[3] = gat_Wn + (size_t)DD * DD;
    wa.src[4] = W_uttr;
    wa.src[5] = W_uttr + (size_t)DD * DD;
    wa.src[6] = W_past;
    wa.src[7] = W_past + (size_t)DD * DD;
    wa.src[8] = W_futr;
    wa.src[9] = W_futr + (size_t)DD * DD;
    wa.src[10] = W_self;
    wprep_kernel<<<(11 * DD * DD + 255) / 256, 256, 0, stream>>>(wa, Wt_all);

    // ---- GAT branch (stats slices 0,1) ----
    // layer 0
    mfma_mm<0, true><<<gMM, 256, 0, stream>>>(f_in, Wt(0), gat_bs, nullptr, tmp1);
    mfma_mm<0, true><<<gMM, 256, 0, stream>>>(f_in, Wt(1), gat_bn, nullptr, tmp2);
    att_kernel<<<gATT, 256, 0, stream>>>(tmp1, gat_as, gat_an, ats_b, atn_b);
    spmm_gat_kernel<<<gSP, 256, 0, stream>>>(tmp2, ats_b, atn_b, row_ptr, col_s, vgs, bufA);
    bn_stats_kernel<false><<<256, 256, 0, stream>>>(bufA, stats(0));
    // layer 1 (input = BN(bufA) via PRE=1, slice 0)
    mfma_mm<1, true><<<gMM, 256, 0, stream>>>(bufA, Wt(2), gat_bs + DD, stats(0), tmp1);
    mfma_mm<1, true><<<gMM, 256, 0, stream>>>(bufA, Wt(3), gat_bn + DD, stats(0), tmp2);
    att_kernel<<<gATT, 256, 0, stream>>>(tmp1, gat_as + DD, gat_an + DD, ats_b, atn_b);
    spmm_gat_kernel<<<gSP, 256, 0, stream>>>(tmp2, ats_b, atn_b, row_ptr, col_s, vgs, bufA);
    bn_stats_kernel<false><<<256, 256, 0, stream>>>(bufA, stats(1));
    cls_acc_kernel<1, true><<<gCA, 256, 0, stream>>>(bufA, W_cls + 0 * NCLS, stats(1), b_cls, out);

    // ---- GCN branches (stats slices 2..7) ----
    const float* vb[3] = {vus, vps, vfs};
    const float* bb[3] = {b_uttr, b_past, b_futr};
    for (int br = 0; br < 3; ++br) {
        int w0 = 4 + br * 2;
        int s0 = 2 + br * 2;
        // layer 0: h = f_in @ W + b (no relu on h)
        mfma_mm<0, false><<<gMM, 256, 0, stream>>>(f_in, Wt(w0), bb[br], nullptr, tmp1);
        spmm_gcn_kernel<<<gSP, 256, 0, stream>>>(tmp1, row_ptr, col_s, vb[br], bufA);
        bn_stats_kernel<true><<<256, 256, 0, stream>>>(bufA, stats(s0));
        // layer 1: input = BN(relu(bufA)) via PRE=2
        mfma_mm<2, false><<<gMM, 256, 0, stream>>>(bufA, Wt(w0 + 1), bb[br] + DD, stats(s0), tmp1);
        spmm_gcn_kernel<<<gSP, 256, 0, stream>>>(tmp1, row_ptr, col_s, vb[br], bufA);
        bn_stats_kernel<true><<<256, 256, 0, stream>>>(bufA, stats(s0 + 1));
        cls_acc_kernel<2, false><<<gCA, 256, 0, stream>>>(
            bufA, W_cls + (size_t)(DD + DD * br) * NCLS, stats(s0 + 1), b_cls, out);
    }

    // ---- self branch (stats slice 8) ----
    mfma_mm<0, true><<<gMM, 256, 0, stream>>>(f_in, Wt(10), b_self, nullptr, tmp1);
    bn_stats_kernel<false><<<256, 256, 0, stream>>>(tmp1, stats(8));
    cls_acc_kernel<1, false><<<gCA, 256, 0, stream>>>(tmp1, W_cls + (size_t)4 * DD * NCLS,
                                                      stats(8), b_cls, out);
}

// Round 3
// 890.593 us; speedup vs baseline: 1.6740x; 1.2668x over previous
//
#include <hip/hip_runtime.h>
#include <hip/hip_bf16.h>

// ---------------------------------------------------------------------------
// ERCGNN R3: bf16 gathers, GCN spmm/matmul algebraic swap (3-way fused L0
// spmm), packed edge scatter, BN-stats fused into MFMA epilogues.
// ---------------------------------------------------------------------------

#define NN 50000
#define NE 500000
#define DD 128
#define NH 8
#define DHD 16
#define NCLS 7
#define SCAN_B 196  // ceil(NN/256)

typedef __attribute__((ext_vector_type(8))) short short8;
typedef __attribute__((ext_vector_type(4))) float f32x4;

__device__ __forceinline__ unsigned short f2bf(float x) {
    unsigned int u = __float_as_uint(x);
    unsigned int r = (u + 0x7fffu + ((u >> 16) & 1u)) >> 16;  // RNE
    return (unsigned short)r;
}
__device__ __forceinline__ unsigned int pack2bf(float lo, float hi) {
    return (unsigned int)f2bf(lo) | ((unsigned int)f2bf(hi) << 16);
}
__device__ __forceinline__ float bflo(unsigned int u) { return __uint_as_float(u << 16); }
__device__ __forceinline__ float bfhi(unsigned int u) { return __uint_as_float(u & 0xffff0000u); }

// ---------------- CSR build ----------------

__global__ void count_kernel(const int* __restrict__ row, int* __restrict__ cnt) {
    int e = blockIdx.x * 256 + threadIdx.x;
    if (e < NE) atomicAdd(&cnt[row[e]], 1);
}

__global__ __launch_bounds__(256) void scan1_kernel(const int* __restrict__ cnt,
                                                    int* __restrict__ pre,
                                                    int* __restrict__ bsum) {
    __shared__ int s[256];
    int t = threadIdx.x;
    int i = blockIdx.x * 256 + t;
    int v = (i < NN) ? cnt[i] : 0;
    s[t] = v;
    __syncthreads();
    for (int off = 1; off < 256; off <<= 1) {
        int u = (t >= off) ? s[t - off] : 0;
        __syncthreads();
        s[t] += u;
        __syncthreads();
    }
    if (i < NN) pre[i] = s[t] - v;
    if (t == 255) bsum[blockIdx.x] = s[255];
}

__global__ __launch_bounds__(256) void scan2_kernel(const int* __restrict__ bsum,
                                                    int* __restrict__ boff) {
    __shared__ int s[256];
    int t = threadIdx.x;
    int v = (t < SCAN_B) ? bsum[t] : 0;
    s[t] = v;
    __syncthreads();
    for (int off = 1; off < 256; off <<= 1) {
        int u = (t >= off) ? s[t - off] : 0;
        __syncthreads();
        s[t] += u;
        __syncthreads();
    }
    boff[t] = s[t] - v;
    if (t == 255) boff[256] = s[255];
}

__global__ __launch_bounds__(256) void scan3_kernel(const int* __restrict__ pre,
                                                    const int* __restrict__ boff,
                                                    int* __restrict__ row_ptr,
                                                    int* __restrict__ fill) {
    int t = threadIdx.x;
    int i = blockIdx.x * 256 + t;
    if (i < NN) {
        int v = pre[i] + boff[blockIdx.x];
        row_ptr[i] = v;
        fill[i] = v;
    }
    if (blockIdx.x == 0 && t == 0) row_ptr[NN] = boff[256];
}

__global__ void scatter_kernel(const int* __restrict__ row, const int* __restrict__ col,
                               const float* __restrict__ vg, const float* __restrict__ vu,
                               const float* __restrict__ vp, const float* __restrict__ vf,
                               int* __restrict__ fill, int2* __restrict__ ed_cg,
                               float4* __restrict__ ed_v3) {
    int e = blockIdx.x * 256 + threadIdx.x;
    if (e >= NE) return;
    int r = row[e];
    int pos = atomicAdd(&fill[r], 1);
    ed_cg[pos] = make_int2(col[e], __float_as_int(vg[e]));
    ed_v3[pos] = make_float4(vu[e], vp[e], vf[e], 0.f);
}

// ---------------- fp32 -> bf16 copy ----------------

__global__ __launch_bounds__(256) void tobf16_kernel(const float* __restrict__ x,
                                                     short* __restrict__ y) {
    int idx = blockIdx.x * 256 + threadIdx.x;  // 8 elems each
    if (idx >= NN * DD / 8) return;
    float4 a = ((const float4*)x)[idx * 2];
    float4 b = ((const float4*)x)[idx * 2 + 1];
    uint4 o;
    o.x = pack2bf(a.x, a.y);
    o.y = pack2bf(a.z, a.w);
    o.z = pack2bf(b.x, b.y);
    o.w = pack2bf(b.z, b.w);
    *(uint4*)(y + (size_t)idx * 8) = o;
}

// ---------------- weight prep: 11x [128][128] fp32 -> col-major bf16 --------

struct WPrepArgs {
    const float* src[11];
};

__global__ __launch_bounds__(256) void wprep_kernel(WPrepArgs a, short* __restrict__ out) {
    int idx = blockIdx.x * 256 + threadIdx.x;
    if (idx >= 11 * DD * DD) return;
    int w = idx >> 14;
    int r = idx & 16383;
    int n = r >> 7, k = r & 127;
    const float* W = a.src[w];
    float v = (w < 4) ? W[(size_t)((n >> 4) * DD + k) * DHD + (n & 15)] : W[(size_t)k * DD + n];
    out[idx] = (short)f2bf(v);
}

// ---------------- MFMA matmul ----------------
// A[N,128] (bf16) @ Wt -> C fp32. RS: bias scaled by rowsum. STATS: 1 = stats
// of stored value, 2 = stats of relu(o) (o stored un-relu'd).

template <bool RELU_OUT, bool RS, int STATS>
__global__ __launch_bounds__(256) void mfma_mm(const short* __restrict__ A,
                                               const short* __restrict__ Wt,
                                               const float* __restrict__ bias,
                                               const float* __restrict__ rs,
                                               float* __restrict__ stats_out,
                                               float* __restrict__ C) {
    __shared__ short As[64 * DD];
    int t = threadIdx.x;
    int r0 = blockIdx.x * 64;
    {
        int srow = t >> 2;
        int sk0 = (t & 3) * 32;
        int grow = r0 + srow;
#pragma unroll
        for (int j = 0; j < 4; ++j) {
            int k0 = sk0 + j * 8;
            short8 frag = {0, 0, 0, 0, 0, 0, 0, 0};
            if (grow < NN) frag = *(const short8*)(A + (size_t)grow * DD + k0);
            int byte = srow * 256 + k0 * 2;
            byte ^= (srow & 7) << 4;
            *(short8*)((char*)As + byte) = frag;
        }
    }
    __syncthreads();

    int w = t >> 6, l = t & 63;
    int c0 = w * 32;
    int lr = l & 15, lg = l >> 4;
    f32x4 acc[4][2] = {};

#pragma unroll
    for (int s = 0; s < 4; ++s) {
        short8 af[4];
#pragma unroll
        for (int f = 0; f < 4; ++f) {
            int rr = f * 16 + lr;
            int byte = rr * 256 + (s * 32 + lg * 8) * 2;
            byte ^= (rr & 7) << 4;
            af[f] = *(const short8*)((const char*)As + byte);
        }
#pragma unroll
        for (int g = 0; g < 2; ++g) {
            int col = c0 + g * 16 + lr;
            short8 bf = *(const short8*)&Wt[(size_t)col * DD + s * 32 + lg * 8];
#pragma unroll
            for (int f = 0; f < 4; ++f)
                acc[f][g] = __builtin_amdgcn_mfma_f32_16x16x32_bf16(af[f], bf, acc[f][g], 0, 0, 0);
        }
    }

    float rsv[4][4];
    if (RS) {
#pragma unroll
        for (int f = 0; f < 4; ++f)
#pragma unroll
            for (int i = 0; i < 4; ++i) {
                int row = r0 + f * 16 + lg * 4 + i;
                rsv[f][i] = (row < NN) ? rs[row] : 0.f;
            }
    }
    float sA[2] = {0.f, 0.f}, qA[2] = {0.f, 0.f};
#pragma unroll
    for (int g = 0; g < 2; ++g) {
        int col = c0 + g * 16 + lr;
        float b = bias[col];
#pragma unroll
        for (int f = 0; f < 4; ++f) {
#pragma unroll
            for (int i = 0; i < 4; ++i) {
                int row = r0 + f * 16 + lg * 4 + i;
                float o = acc[f][g][i] + (RS ? rsv[f][i] * b : b);
                if (RELU_OUT) o = fmaxf(o, 0.f);
                if (row < NN) {
                    C[(size_t)row * DD + col] = o;
                    if (STATS) {
                        float v = (STATS == 2) ? fmaxf(o, 0.f) : o;
                        sA[g] += v;
                        qA[g] += v * v;
                    }
                }
            }
        }
    }
    if (STATS) {
#pragma unroll
        for (int g = 0; g < 2; ++g) {
            sA[g] += __shfl_xor(sA[g], 16);
            sA[g] += __shfl_xor(sA[g], 32);
            qA[g] += __shfl_xor(qA[g], 16);
            qA[g] += __shfl_xor(qA[g], 32);
        }
        if (lg == 0) {
#pragma unroll
            for (int g = 0; g < 2; ++g) {
                int col = c0 + g * 16 + lr;
                atomicAdd(&stats_out[col], sA[g]);
                atomicAdd(&stats_out[DD + col], qA[g]);
            }
        }
    }
}

// ---- paired matmul (GAT): one staged A, two weights; out1 fp32 relu, out2 bf16 relu
// PRE: 0 = A bf16 no preprocess; 1 = A fp32 with BN(stats_in)

template <int PRE>
__global__ __launch_bounds__(256) void mfma_mm_pair(const void* __restrict__ Av,
                                                    const short* __restrict__ Wt1,
                                                    const short* __restrict__ Wt2,
                                                    const float* __restrict__ b1,
                                                    const float* __restrict__ b2,
                                                    const float* __restrict__ stats_in,
                                                    float* __restrict__ out1,
                                                    short* __restrict__ out2) {
    __shared__ short As[64 * DD];
    __shared__ float mS[DD], sS[DD];
    int t = threadIdx.x;
    int r0 = blockIdx.x * 64;

    if (PRE == 1) {
        if (t < DD) {
            const float inv_n = 1.0f / (float)NN;
            float m = stats_in[t] * inv_n;
            float var = stats_in[DD + t] * inv_n - m * m;
            mS[t] = m;
            sS[t] = rsqrtf(var + 1e-9f);
        }
        __syncthreads();
    }
    {
        int srow = t >> 2;
        int sk0 = (t & 3) * 32;
        int grow = r0 + srow;
#pragma unroll
        for (int j = 0; j < 4; ++j) {
            int k0 = sk0 + j * 8;
            short8 frag = {0, 0, 0, 0, 0, 0, 0, 0};
            if (grow < NN) {
                if (PRE == 0) {
                    frag = *(const short8*)((const short*)Av + (size_t)grow * DD + k0);
                } else {
                    const float* Ar = (const float*)Av + (size_t)grow * DD;
                    float4 v0 = *(const float4*)(Ar + k0);
                    float4 v1 = *(const float4*)(Ar + k0 + 4);
                    float vv[8] = {v0.x, v0.y, v0.z, v0.w, v1.x, v1.y, v1.z, v1.w};
#pragma unroll
                    for (int e = 0; e < 8; ++e)
                        frag[e] = (short)f2bf((vv[e] - mS[k0 + e]) * sS[k0 + e]);
                }
            }
            int byte = srow * 256 + k0 * 2;
            byte ^= (srow & 7) << 4;
            *(short8*)((char*)As + byte) = frag;
        }
    }
    __syncthreads();

    int w = t >> 6, l = t & 63;
    int c0 = w * 32;
    int lr = l & 15, lg = l >> 4;
    f32x4 acc1[4][2] = {}, acc2[4][2] = {};

#pragma unroll
    for (int s = 0; s < 4; ++s) {
        short8 af[4];
#pragma unroll
        for (int f = 0; f < 4; ++f) {
            int rr = f * 16 + lr;
            int byte = rr * 256 + (s * 32 + lg * 8) * 2;
            byte ^= (rr & 7) << 4;
            af[f] = *(const short8*)((const char*)As + byte);
        }
#pragma unroll
        for (int g = 0; g < 2; ++g) {
            int col = c0 + g * 16 + lr;
            short8 bfa = *(const short8*)&Wt1[(size_t)col * DD + s * 32 + lg * 8];
            short8 bfb = *(const short8*)&Wt2[(size_t)col * DD + s * 32 + lg * 8];
#pragma unroll
            for (int f = 0; f < 4; ++f) {
                acc1[f][g] = __builtin_amdgcn_mfma_f32_16x16x32_bf16(af[f], bfa, acc1[f][g], 0, 0, 0);
                acc2[f][g] = __builtin_amdgcn_mfma_f32_16x16x32_bf16(af[f], bfb, acc2[f][g], 0, 0, 0);
            }
        }
    }
#pragma unroll
    for (int g = 0; g < 2; ++g) {
        int col = c0 + g * 16 + lr;
        float bb1 = b1[col], bb2 = b2[col];
#pragma unroll
        for (int f = 0; f < 4; ++f) {
#pragma unroll
            for (int i = 0; i < 4; ++i) {
                int row = r0 + f * 16 + lg * 4 + i;
                if (row < NN) {
                    float o1 = fmaxf(acc1[f][g][i] + bb1, 0.f);
                    float o2 = fmaxf(acc2[f][g][i] + bb2, 0.f);
                    out1[(size_t)row * DD + col] = o1;
                    out2[(size_t)row * DD + col] = (short)f2bf(o2);
                }
            }
        }
    }
}

// ---------------- GAT attention scalars ----------------

__global__ void att_kernel(const float* __restrict__ hs, const float* __restrict__ a_s,
                           const float* __restrict__ a_n, float* __restrict__ ats,
                           float* __restrict__ atn) {
    int idx = blockIdx.x * 256 + threadIdx.x;
    if (idx >= NN * NH) return;
    int h = idx & 7;
    int n = idx >> 3;
    const float* hp = hs + (size_t)n * DD + h * DHD;
    const float* asp = a_s + h * DHD;
    const float* anp = a_n + h * DHD;
    float ds = 0.f, dn = 0.f;
#pragma unroll
    for (int k = 0; k < DHD; ++k) {
        float v = hp[k];
        ds += v * asp[k];
        dn += v * anp[k];
    }
    ats[idx] = ds > 0.f ? ds : 0.2f * ds;
    atn[idx] = dn > 0.f ? dn : 0.2f * dn;
}

// ---------------- SpMMs (wave per row, bf16 gathers) ----------------

__global__ __launch_bounds__(256) void spmm3_kernel(const short* __restrict__ fbf,
                                                    const int2* __restrict__ ed_cg,
                                                    const float4* __restrict__ ed_v3,
                                                    const int* __restrict__ row_ptr,
                                                    short* __restrict__ zu, short* __restrict__ zp,
                                                    short* __restrict__ zf,
                                                    float* __restrict__ rs_all) {
    int r = (blockIdx.x * 256 + threadIdx.x) >> 6;
    int lane = threadIdx.x & 63;
    if (r >= NN) return;
    int start = row_ptr[r], end = row_ptr[r + 1];
    float2 au = {0.f, 0.f}, ap = {0.f, 0.f}, af_ = {0.f, 0.f};
    float su = 0.f, sp = 0.f, sf = 0.f;
    for (int j = start; j < end; ++j) {
        int c = ed_cg[j].x;
        float4 v = ed_v3[j];
        unsigned int u = *(const unsigned int*)(fbf + (size_t)c * DD + lane * 2);
        float lo = bflo(u), hi = bfhi(u);
        au.x += v.x * lo; au.y += v.x * hi;
        ap.x += v.y * lo; ap.y += v.y * hi;
        af_.x += v.z * lo; af_.y += v.z * hi;
        su += v.x; sp += v.y; sf += v.z;
    }
    *(unsigned int*)(zu + (size_t)r * DD + lane * 2) = pack2bf(au.x, au.y);
    *(unsigned int*)(zp + (size_t)r * DD + lane * 2) = pack2bf(ap.x, ap.y);
    *(unsigned int*)(zf + (size_t)r * DD + lane * 2) = pack2bf(af_.x, af_.y);
    if (lane == 0) {
        rs_all[r] = su;
        rs_all[NN + r] = sp;
        rs_all[2 * NN + r] = sf;
    }
}

__global__ __launch_bounds__(256) void spmm_gat_kernel(const short* __restrict__ hnb,
                                                       const float* __restrict__ ats,
                                                       const float* __restrict__ atn,
                                                       const int2* __restrict__ ed_cg,
                                                       const int* __restrict__ row_ptr,
                                                       float* __restrict__ agg) {
    int r = (blockIdx.x * 256 + threadIdx.x) >> 6;
    int lane = threadIdx.x & 63;
    if (r >= NN) return;
    int hh = lane >> 3;
    float a_s = ats[r * NH + hh];
    int start = row_ptr[r], end = row_ptr[r + 1];
    float2 acc = {0.f, 0.f};
    for (int j = start; j < end; ++j) {
        int2 cg = ed_cg[j];
        float e = (a_s + atn[cg.x * NH + hh]) * __int_as_float(cg.y);
        unsigned int u = *(const unsigned int*)(hnb + (size_t)cg.x * DD + lane * 2);
        acc.x += e * bflo(u);
        acc.y += e * bfhi(u);
    }
    *(float2*)&agg[(size_t)r * DD + lane * 2] = acc;
}

template <int COMP>
__global__ __launch_bounds__(256) void spmm_gcn1_kernel(const short* __restrict__ f1b,
                                                        const int2* __restrict__ ed_cg,
                                                        const float4* __restrict__ ed_v3,
                                                        const int* __restrict__ row_ptr,
                                                        short* __restrict__ z1) {
    int r = (blockIdx.x * 256 + threadIdx.x) >> 6;
    int lane = threadIdx.x & 63;
    if (r >= NN) return;
    int start = row_ptr[r], end = row_ptr[r + 1];
    float2 acc = {0.f, 0.f};
    for (int j = start; j < end; ++j) {
        int c = ed_cg[j].x;
        float4 v = ed_v3[j];
        float w = (COMP == 0) ? v.x : (COMP == 1) ? v.y : v.z;
        unsigned int u = *(const unsigned int*)(f1b + (size_t)c * DD + lane * 2);
        acc.x += w * bflo(u);
        acc.y += w * bfhi(u);
    }
    *(unsigned int*)(z1 + (size_t)r * DD + lane * 2) = pack2bf(acc.x, acc.y);
}

// ---------------- BN stats (GAT agg only) ----------------

__global__ __launch_bounds__(256) void bn_stats_kernel(const float* __restrict__ x,
                                                       float* __restrict__ stats) {
    int c = threadIdx.x & 127;
    int sub = threadIdx.x >> 7;
    int rows_per_block = (NN + gridDim.x - 1) / gridDim.x;
    int rbeg = blockIdx.x * rows_per_block;
    int rend = min(rbeg + rows_per_block, NN);
    float s = 0.f, q = 0.f;
    for (int r = rbeg + sub; r < rend; r += 2) {
        float v = x[(size_t)r * DD + c];
        s += v;
        q += v * v;
    }
    atomicAdd(&stats[c], s);
    atomicAdd(&stats[DD + c], q);
}

// ---------------- BN(relu(h)) -> bf16 ----------------

__global__ __launch_bounds__(256) void bnapply_bf16_kernel(const float* __restrict__ h,
                                                           const float* __restrict__ stats,
                                                           short* __restrict__ outb) {
    __shared__ float mS[DD], sS[DD];
    int t = threadIdx.x;
    if (t < DD) {
        const float inv_n = 1.0f / (float)NN;
        float m = stats[t] * inv_n;
        float var = stats[DD + t] * inv_n - m * m;
        mS[t] = m;
        sS[t] = rsqrtf(var + 1e-9f);
    }
    __syncthreads();
    int idx = blockIdx.x * 256 + t;  // 8 elems each
    if (idx >= NN * DD / 8) return;
    int c0 = (idx & 15) * 8;
    float4 a = ((const float4*)h)[idx * 2];
    float4 b = ((const float4*)h)[idx * 2 + 1];
    float vv[8] = {a.x, a.y, a.z, a.w, b.x, b.y, b.z, b.w};
#pragma unroll
    for (int e = 0; e < 8; ++e) vv[e] = (fmaxf(vv[e], 0.f) - mS[c0 + e]) * sS[c0 + e];
    uint4 o;
    o.x = pack2bf(vv[0], vv[1]);
    o.y = pack2bf(vv[2], vv[3]);
    o.z = pack2bf(vv[4], vv[5]);
    o.w = pack2bf(vv[6], vv[7]);
    *(uint4*)(outb + (size_t)idx * 8) = o;
}

// ---------------- classifier ----------------

template <int PRE, bool FIRST>
__global__ __launch_bounds__(256) void cls_acc_kernel(const float* __restrict__ o,
                                                      const float* __restrict__ Wc,
                                                      const float* __restrict__ stats,
                                                      const float* __restrict__ b_cls,
                                                      float* __restrict__ out) {
    __shared__ float Wl[DD * NCLS];
    __shared__ float mS[DD], sS[DD];
    int t = threadIdx.x;
    for (int i = t; i < DD * NCLS; i += 256) Wl[i] = Wc[i];
    if (PRE && t < DD) {
        const float inv_n = 1.0f / (float)NN;
        float m = stats[t] * inv_n;
        float var = stats[DD + t] * inv_n - m * m;
        mS[t] = m;
        sS[t] = rsqrtf(var + 1e-9f);
    }
    __syncthreads();
    int n = blockIdx.x * 256 + t;
    if (n >= NN) return;
    float acc[NCLS] = {};
    const float4* orow = (const float4*)(o + (size_t)n * DD);
    for (int k4 = 0; k4 < DD / 4; ++k4) {
        float4 v = orow[k4];
#pragma unroll
        for (int kk = 0; kk < 4; ++kk) {
            int k = k4 * 4 + kk;
            float a = ((const float*)&v)[kk];
            if (PRE == 2) a = fmaxf(a, 0.f);
            if (PRE) a = (a - mS[k]) * sS[k];
#pragma unroll
            for (int c = 0; c < NCLS; ++c) acc[c] += a * Wl[k * NCLS + c];
        }
    }
#pragma unroll
    for (int c = 0; c < NCLS; ++c) {
        if (FIRST)
            out[n * NCLS + c] = acc[c] + b_cls[c];
        else
            out[n * NCLS + c] += acc[c];
    }
}

// ---------------------------------------------------------------------------

extern "C" void kernel_launch(void* const* d_in, const int* in_sizes, int n_in, void* d_out,
                              int out_size, void* d_ws, size_t ws_size, hipStream_t stream) {
    const float* f_in = (const float*)d_in[0];
    const int* edge_row = (const int*)d_in[1];
    const int* edge_col = (const int*)d_in[2];
    const float* vals_gat = (const float*)d_in[3];
    const float* vals_uttr = (const float*)d_in[4];
    const float* vals_past = (const float*)d_in[5];
    const float* vals_futr = (const float*)d_in[6];
    const float* gat_Ws = (const float*)d_in[7];
    const float* gat_bs = (const float*)d_in[8];
    const float* gat_Wn = (const float*)d_in[9];
    const float* gat_bn = (const float*)d_in[10];
    const float* gat_as = (const float*)d_in[11];
    const float* gat_an = (const float*)d_in[12];
    const float* W_uttr = (const float*)d_in[13];
    const float* b_uttr = (const float*)d_in[14];
    const float* W_past = (const float*)d_in[15];
    const float* b_past = (const float*)d_in[16];
    const float* W_futr = (const float*)d_in[17];
    const float* b_futr = (const float*)d_in[18];
    const float* W_self = (const float*)d_in[19];
    const float* b_self = (const float*)d_in[20];
    const float* W_cls = (const float*)d_in[21];
    const float* b_cls = (const float*)d_in[22];
    float* out = (float*)d_out;

    char* ws = (char*)d_ws;
    size_t off = 0;
    auto alloc = [&](size_t bytes) -> void* {
        void* p = ws + off;
        off = (off + bytes + 255) & ~(size_t)255;
        return p;
    };
    float* stats_all = (float*)alloc(9 * 2 * DD * 4);
    int* cnt = (int*)alloc((size_t)NN * 4);  // adjacent to stats -> one memset
    float* tmp1 = (float*)alloc((size_t)NN * DD * 4);   // hs / h0 / h1 / self-h
    float* bufA = (float*)alloc((size_t)NN * DD * 4);   // GAT agg
    short* fbf = (short*)alloc((size_t)NN * DD * 2);    // f_in bf16
    short* hnb = (short*)alloc((size_t)NN * DD * 2);    // GAT hn bf16; reused as GCN f1b
    short* z0u = (short*)alloc((size_t)NN * DD * 2);
    short* z0p = (short*)alloc((size_t)NN * DD * 2);
    short* z0f = (short*)alloc((size_t)NN * DD * 2);
    float* rs_all = (float*)alloc((size_t)3 * NN * 4);
    float* ats_b = (float*)alloc((size_t)NN * NH * 4);
    float* atn_b = (float*)alloc((size_t)NN * NH * 4);
    short* Wt_all = (short*)alloc((size_t)11 * DD * DD * 2);
    int* row_ptr = (int*)alloc((size_t)(NN + 1) * 4);
    int* fill = (int*)alloc((size_t)NN * 4);
    int* pre_b = (int*)alloc((size_t)NN * 4);
    int* bsum = (int*)alloc((size_t)SCAN_B * 4);
    int* boff = (int*)alloc((size_t)257 * 4);
    int2* ed_cg = (int2*)alloc((size_t)NE * 8);
    float4* ed_v3 = (float4*)alloc((size_t)NE * 16);

    auto stats = [&](int s) { return stats_all + (size_t)s * 2 * DD; };
    auto Wt = [&](int w) { return Wt_all + (size_t)w * DD * DD; };
    short* z0[3] = {z0u, z0p, z0f};

    const int gE = (NE + 255) / 256;
    const int gMM = (NN + 63) / 64;
    const int gATT = (NN * NH + 255) / 256;
    const int gSP = (NN + 3) / 4;
    const int gCA = (NN + 255) / 256;
    const int gBF = (NN * DD / 8 + 255) / 256;

    hipMemsetAsync(stats_all, 0, 9 * 2 * DD * 4 + (size_t)NN * 4, stream);

    // CSR build
    count_kernel<<<gE, 256, 0, stream>>>(edge_row, cnt);
    scan1_kernel<<<SCAN_B, 256, 0, stream>>>(cnt, pre_b, bsum);
    scan2_kernel<<<1, 256, 0, stream>>>(bsum, boff);
    scan3_kernel<<<SCAN_B, 256, 0, stream>>>(pre_b, boff, row_ptr, fill);
    scatter_kernel<<<gE, 256, 0, stream>>>(edge_row, edge_col, vals_gat, vals_uttr, vals_past,
                                           vals_futr, fill, ed_cg, ed_v3);

    tobf16_kernel<<<gBF, 256, 0, stream>>>(f_in, fbf);

    WPrepArgs wa;
    wa.src[0] = gat_Ws;
    wa.src[1] = gat_Wn;
    wa.src[2] = gat_Ws + (size_t)DD * DD;
    wa.src[3] = gat_Wn + (size_t)DD * DD;
    wa.src[4] = W_uttr;
    wa.src[5] = W_uttr + (size_t)DD * DD;
    wa.src[6] = W_past;
    wa.src[7] = W_past + (size_t)DD * DD;
    wa.src[8] = W_futr;
    wa.src[9] = W_futr + (size_t)DD * DD;
    wa.src[10] = W_self;
    wprep_kernel<<<(11 * DD * DD + 255) / 256, 256, 0, stream>>>(wa, Wt_all);

    // ---- GAT branch ----
    mfma_mm_pair<0><<<gMM, 256, 0, stream>>>(fbf, Wt(0), Wt(1), gat_bs, gat_bn, nullptr, tmp1, hnb);
    att_kernel<<<gATT, 256, 0, stream>>>(tmp1, gat_as, gat_an, ats_b, atn_b);
    spmm_gat_kernel<<<gSP, 256, 0, stream>>>(hnb, ats_b, atn_b, ed_cg, row_ptr, bufA);
    bn_stats_kernel<<<256, 256, 0, stream>>>(bufA, stats(0));
    mfma_mm_pair<1><<<gMM, 256, 0, stream>>>(bufA, Wt(2), Wt(3), gat_bs + DD, gat_bn + DD,
                                             stats(0), tmp1, hnb);
    att_kernel<<<gATT, 256, 0, stream>>>(tmp1, gat_as + DD, gat_an + DD, ats_b, atn_b);
    spmm_gat_kernel<<<gSP, 256, 0, stream>>>(hnb, ats_b, atn_b, ed_cg, row_ptr, bufA);
    bn_stats_kernel<<<256, 256, 0, stream>>>(bufA, stats(1));
    cls_acc_kernel<1, true><<<gCA, 256, 0, stream>>>(bufA, W_cls, stats(1), b_cls, out);

    // ---- GCN branches: z0 = S_br f_in (fused), then h = z @ W + rs*b ----
    spmm3_kernel<<<gSP, 256, 0, stream>>>(fbf, ed_cg, ed_v3, row_ptr, z0u, z0p, z0f, rs_all);

    const float* bb[3] = {b_uttr, b_past, b_futr};
    for (int br = 0; br < 3; ++br) {
        int w0 = 4 + br * 2;
        int s0 = 2 + br * 2;
        float* rs = rs_all + (size_t)br * NN;
        // layer 0: h0 = z0 @ W0 + rs*b0, stats of relu(h0)
        mfma_mm<false, true, 2><<<gMM, 256, 0, stream>>>(z0[br], Wt(w0), bb[br], rs, stats(s0),
                                                         tmp1);
        // f1 = BN(relu(h0)) -> bf16
        bnapply_bf16_kernel<<<gBF, 256, 0, stream>>>(tmp1, stats(s0), hnb);
        // z1 = S_br f1 (reuse z0[br] storage)
        if (br == 0)
            spmm_gcn1_kernel<0><<<gSP, 256, 0, stream>>>(hnb, ed_cg, ed_v3, row_ptr, z0[br]);
        else if (br == 1)
            spmm_gcn1_kernel<1><<<gSP, 256, 0, stream>>>(hnb, ed_cg, ed_v3, row_ptr, z0[br]);
        else
            spmm_gcn1_kernel<2><<<gSP, 256, 0, stream>>>(hnb, ed_cg, ed_v3, row_ptr, z0[br]);
        // layer 1: h1 = z1 @ W1 + rs*b1, stats of relu(h1)
        mfma_mm<false, true, 2><<<gMM, 256, 0, stream>>>(z0[br], Wt(w0 + 1), bb[br] + DD, rs,
                                                         stats(s0 + 1), tmp1);
        cls_acc_kernel<2, false><<<gCA, 256, 0, stream>>>(
            tmp1, W_cls + (size_t)(DD + DD * br) * NCLS, stats(s0 + 1), b_cls, out);
    }

    // ---- self branch ----
    mfma_mm<true, false, 1><<<gMM, 256, 0, stream>>>(fbf, Wt(10), b_self, nullptr, stats(8), tmp1);
    cls_acc_kernel<1, false><<<gCA, 256, 0, stream>>>(tmp1, W_cls + (size_t)4 * DD * NCLS,
                                                      stats(8), b_cls, out);
}

// Round 4
// 664.521 us; speedup vs baseline: 2.2435x; 1.3402x over previous
//
#include <hip/hip_runtime.h>
#include <hip/hip_bf16.h>

// ---------------------------------------------------------------------------
// ERCGNN R4: 3 fused gather passes (GAT-L0+GCN-L0 fused; GCN-L1 x3 fused),
// unroll-2 gather loops w/ scalar edge-record loads, 32B edge records,
// attention fused into MFMA pair epilogue (shfl_xor reduce).
// ---------------------------------------------------------------------------

#define NN 50000
#define NE 500000
#define DD 128
#define NH 8
#define DHD 16
#define NCLS 7
#define SCAN_B 196  // ceil(50000/256)

typedef __attribute__((ext_vector_type(8))) short short8;
typedef __attribute__((ext_vector_type(4))) float f32x4;

__device__ __forceinline__ unsigned short f2bf(float x) {
    unsigned int u = __float_as_uint(x);
    unsigned int r = (u + 0x7fffu + ((u >> 16) & 1u)) >> 16;  // RNE
    return (unsigned short)r;
}
__device__ __forceinline__ unsigned int pack2bf(float lo, float hi) {
    return (unsigned int)f2bf(lo) | ((unsigned int)f2bf(hi) << 16);
}
__device__ __forceinline__ float bflo(unsigned int u) { return __uint_as_float(u << 16); }
__device__ __forceinline__ float bfhi(unsigned int u) { return __uint_as_float(u & 0xffff0000u); }

// ---------------- CSR build ----------------

__global__ void count_kernel(const int* __restrict__ row, int* __restrict__ cnt) {
    int e = blockIdx.x * 256 + threadIdx.x;
    if (e < NE) atomicAdd(&cnt[row[e]], 1);
}

__global__ __launch_bounds__(256) void scan1_kernel(const int* __restrict__ cnt,
                                                    int* __restrict__ pre,
                                                    int* __restrict__ bsum) {
    __shared__ int s[256];
    int t = threadIdx.x;
    int i = blockIdx.x * 256 + t;
    int v = (i < NN) ? cnt[i] : 0;
    s[t] = v;
    __syncthreads();
    for (int off = 1; off < 256; off <<= 1) {
        int u = (t >= off) ? s[t - off] : 0;
        __syncthreads();
        s[t] += u;
        __syncthreads();
    }
    if (i < NN) pre[i] = s[t] - v;
    if (t == 255) bsum[blockIdx.x] = s[255];
}

__global__ __launch_bounds__(256) void scan2_kernel(const int* __restrict__ bsum,
                                                    int* __restrict__ boff) {
    __shared__ int s[256];
    int t = threadIdx.x;
    int v = (t < SCAN_B) ? bsum[t] : 0;
    s[t] = v;
    __syncthreads();
    for (int off = 1; off < 256; off <<= 1) {
        int u = (t >= off) ? s[t - off] : 0;
        __syncthreads();
        s[t] += u;
        __syncthreads();
    }
    boff[t] = s[t] - v;
    if (t == 255) boff[256] = s[255];
}

__global__ __launch_bounds__(256) void scan3_kernel(const int* __restrict__ pre,
                                                    const int* __restrict__ boff,
                                                    int* __restrict__ row_ptr,
                                                    int* __restrict__ fill) {
    int t = threadIdx.x;
    int i = blockIdx.x * 256 + t;
    if (i < NN) {
        int v = pre[i] + boff[blockIdx.x];
        row_ptr[i] = v;
        fill[i] = v;
    }
    if (blockIdx.x == 0 && t == 0) row_ptr[NN] = boff[256];
}

// 32B edge record: {col, vg, vu, vp} {vf, 0, 0, 0}
__global__ void scatter_kernel(const int* __restrict__ row, const int* __restrict__ col,
                               const float* __restrict__ vg, const float* __restrict__ vu,
                               const float* __restrict__ vp, const float* __restrict__ vf,
                               int* __restrict__ fill, int4* __restrict__ ed) {
    int e = blockIdx.x * 256 + threadIdx.x;
    if (e >= NE) return;
    int r = row[e];
    int pos = atomicAdd(&fill[r], 1);
    ed[2 * pos] = make_int4(col[e], __float_as_int(vg[e]), __float_as_int(vu[e]),
                            __float_as_int(vp[e]));
    ed[2 * pos + 1] = make_int4(__float_as_int(vf[e]), 0, 0, 0);
}

// ---------------- fp32 -> bf16 copy ----------------

__global__ __launch_bounds__(256) void tobf16_kernel(const float* __restrict__ x,
                                                     short* __restrict__ y) {
    int idx = blockIdx.x * 256 + threadIdx.x;
    if (idx >= NN * DD / 8) return;
    float4 a = ((const float4*)x)[idx * 2];
    float4 b = ((const float4*)x)[idx * 2 + 1];
    uint4 o;
    o.x = pack2bf(a.x, a.y);
    o.y = pack2bf(a.z, a.w);
    o.z = pack2bf(b.x, b.y);
    o.w = pack2bf(b.z, b.w);
    *(uint4*)(y + (size_t)idx * 8) = o;
}

// ---------------- weight prep ----------------

struct WPrepArgs {
    const float* src[11];
};

__global__ __launch_bounds__(256) void wprep_kernel(WPrepArgs a, short* __restrict__ out) {
    int idx = blockIdx.x * 256 + threadIdx.x;
    if (idx >= 11 * DD * DD) return;
    int w = idx >> 14;
    int r = idx & 16383;
    int n = r >> 7, k = r & 127;
    const float* W = a.src[w];
    float v = (w < 4) ? W[(size_t)((n >> 4) * DD + k) * DHD + (n & 15)] : W[(size_t)k * DD + n];
    out[idx] = (short)f2bf(v);
}

// ---------------- MFMA matmul (single) ----------------
// STATS: 1 = stats of stored value, 2 = stats of relu(o) (o stored raw)

template <bool RELU_OUT, bool RS, int STATS>
__global__ __launch_bounds__(256) void mfma_mm(const short* __restrict__ A,
                                               const short* __restrict__ Wt,
                                               const float* __restrict__ bias,
                                               const float* __restrict__ rs,
                                               float* __restrict__ stats_out,
                                               float* __restrict__ C) {
    __shared__ short As[64 * DD];
    int t = threadIdx.x;
    int r0 = blockIdx.x * 64;
    {
        int srow = t >> 2;
        int sk0 = (t & 3) * 32;
        int grow = r0 + srow;
#pragma unroll
        for (int j = 0; j < 4; ++j) {
            int k0 = sk0 + j * 8;
            short8 frag = {0, 0, 0, 0, 0, 0, 0, 0};
            if (grow < NN) frag = *(const short8*)(A + (size_t)grow * DD + k0);
            int byte = srow * 256 + k0 * 2;
            byte ^= (srow & 7) << 4;
            *(short8*)((char*)As + byte) = frag;
        }
    }
    __syncthreads();

    int w = t >> 6, l = t & 63;
    int c0 = w * 32;
    int lr = l & 15, lg = l >> 4;
    f32x4 acc[4][2] = {};

#pragma unroll
    for (int s = 0; s < 4; ++s) {
        short8 af[4];
#pragma unroll
        for (int f = 0; f < 4; ++f) {
            int rr = f * 16 + lr;
            int byte = rr * 256 + (s * 32 + lg * 8) * 2;
            byte ^= (rr & 7) << 4;
            af[f] = *(const short8*)((const char*)As + byte);
        }
#pragma unroll
        for (int g = 0; g < 2; ++g) {
            int col = c0 + g * 16 + lr;
            short8 bf = *(const short8*)&Wt[(size_t)col * DD + s * 32 + lg * 8];
#pragma unroll
            for (int f = 0; f < 4; ++f)
                acc[f][g] = __builtin_amdgcn_mfma_f32_16x16x32_bf16(af[f], bf, acc[f][g], 0, 0, 0);
        }
    }

    float rsv[4][4];
    if (RS) {
#pragma unroll
        for (int f = 0; f < 4; ++f)
#pragma unroll
            for (int i = 0; i < 4; ++i) {
                int row = r0 + f * 16 + lg * 4 + i;
                rsv[f][i] = (row < NN) ? rs[row] : 0.f;
            }
    }
    float sA[2] = {0.f, 0.f}, qA[2] = {0.f, 0.f};
#pragma unroll
    for (int g = 0; g < 2; ++g) {
        int col = c0 + g * 16 + lr;
        float b = bias[col];
#pragma unroll
        for (int f = 0; f < 4; ++f) {
#pragma unroll
            for (int i = 0; i < 4; ++i) {
                int row = r0 + f * 16 + lg * 4 + i;
                float o = acc[f][g][i] + (RS ? rsv[f][i] * b : b);
                if (RELU_OUT) o = fmaxf(o, 0.f);
                if (row < NN) {
                    C[(size_t)row * DD + col] = o;
                    if (STATS) {
                        float v = (STATS == 2) ? fmaxf(o, 0.f) : o;
                        sA[g] += v;
                        qA[g] += v * v;
                    }
                }
            }
        }
    }
    if (STATS) {
#pragma unroll
        for (int g = 0; g < 2; ++g) {
            sA[g] += __shfl_xor(sA[g], 16);
            sA[g] += __shfl_xor(sA[g], 32);
            qA[g] += __shfl_xor(qA[g], 16);
            qA[g] += __shfl_xor(qA[g], 32);
        }
        if (lg == 0) {
#pragma unroll
            for (int g = 0; g < 2; ++g) {
                int col = c0 + g * 16 + lr;
                atomicAdd(&stats_out[col], sA[g]);
                atomicAdd(&stats_out[DD + col], qA[g]);
            }
        }
    }
}

// ---- GAT pair matmul with FUSED attention (hs never hits memory) ----
// PRE: 0 = A bf16; 1 = A fp32 with BN(stats_in). Outputs: hn bf16, ats, atn.

template <int PRE>
__global__ __launch_bounds__(256) void mfma_mm_pair(const void* __restrict__ Av,
                                                    const short* __restrict__ Wt1,
                                                    const short* __restrict__ Wt2,
                                                    const float* __restrict__ b1,
                                                    const float* __restrict__ b2,
                                                    const float* __restrict__ a_se,
                                                    const float* __restrict__ a_ne,
                                                    const float* __restrict__ stats_in,
                                                    short* __restrict__ out2,
                                                    float* __restrict__ ats_o,
                                                    float* __restrict__ atn_o) {
    __shared__ short As[64 * DD];
    __shared__ float mS[DD], sS[DD];
    int t = threadIdx.x;
    int r0 = blockIdx.x * 64;

    if (PRE == 1) {
        if (t < DD) {
            const float inv_n = 1.0f / (float)NN;
            float m = stats_in[t] * inv_n;
            float var = stats_in[DD + t] * inv_n - m * m;
            mS[t] = m;
            sS[t] = rsqrtf(var + 1e-9f);
        }
        __syncthreads();
    }
    {
        int srow = t >> 2;
        int sk0 = (t & 3) * 32;
        int grow = r0 + srow;
#pragma unroll
        for (int j = 0; j < 4; ++j) {
            int k0 = sk0 + j * 8;
            short8 frag = {0, 0, 0, 0, 0, 0, 0, 0};
            if (grow < NN) {
                if (PRE == 0) {
                    frag = *(const short8*)((const short*)Av + (size_t)grow * DD + k0);
                } else {
                    const float* Ar = (const float*)Av + (size_t)grow * DD;
                    float4 v0 = *(const float4*)(Ar + k0);
                    float4 v1 = *(const float4*)(Ar + k0 + 4);
                    float vv[8] = {v0.x, v0.y, v0.z, v0.w, v1.x, v1.y, v1.z, v1.w};
#pragma unroll
                    for (int e = 0; e < 8; ++e)
                        frag[e] = (short)f2bf((vv[e] - mS[k0 + e]) * sS[k0 + e]);
                }
            }
            int byte = srow * 256 + k0 * 2;
            byte ^= (srow & 7) << 4;
            *(short8*)((char*)As + byte) = frag;
        }
    }
    __syncthreads();

    int w = t >> 6, l = t & 63;
    int c0 = w * 32;
    int lr = l & 15, lg = l >> 4;
    f32x4 acc1[4][2] = {}, acc2[4][2] = {};

#pragma unroll
    for (int s = 0; s < 4; ++s) {
        short8 af[4];
#pragma unroll
        for (int f = 0; f < 4; ++f) {
            int rr = f * 16 + lr;
            int byte = rr * 256 + (s * 32 + lg * 8) * 2;
            byte ^= (rr & 7) << 4;
            af[f] = *(const short8*)((const char*)As + byte);
        }
#pragma unroll
        for (int g = 0; g < 2; ++g) {
            int col = c0 + g * 16 + lr;
            short8 bfa = *(const short8*)&Wt1[(size_t)col * DD + s * 32 + lg * 8];
            short8 bfb = *(const short8*)&Wt2[(size_t)col * DD + s * 32 + lg * 8];
#pragma unroll
            for (int f = 0; f < 4; ++f) {
                acc1[f][g] = __builtin_amdgcn_mfma_f32_16x16x32_bf16(af[f], bfa, acc1[f][g], 0, 0, 0);
                acc2[f][g] = __builtin_amdgcn_mfma_f32_16x16x32_bf16(af[f], bfb, acc2[f][g], 0, 0, 0);
            }
        }
    }
    // epilogue: store hn bf16; reduce attention dots across the 16 lanes (lr)
    // that hold one head's 16 cols. head h = (c0>>4)+g, kk = lr.
#pragma unroll
    for (int g = 0; g < 2; ++g) {
        int colc = c0 + g * 16 + lr;
        float bb1 = b1[colc], bb2 = b2[colc];
        float asv = a_se[colc], anv = a_ne[colc];
        int h = (c0 >> 4) + g;
#pragma unroll
        for (int f = 0; f < 4; ++f) {
#pragma unroll
            for (int i = 0; i < 4; ++i) {
                int row = r0 + f * 16 + lg * 4 + i;
                float o1 = fmaxf(acc1[f][g][i] + bb1, 0.f);  // hs (ephemeral)
                float o2 = fmaxf(acc2[f][g][i] + bb2, 0.f);  // hn
                if (row < NN) out2[(size_t)row * DD + colc] = (short)f2bf(o2);
                float ds = o1 * asv, dn = o1 * anv;
                ds += __shfl_xor(ds, 1);
                dn += __shfl_xor(dn, 1);
                ds += __shfl_xor(ds, 2);
                dn += __shfl_xor(dn, 2);
                ds += __shfl_xor(ds, 4);
                dn += __shfl_xor(dn, 4);
                ds += __shfl_xor(ds, 8);
                dn += __shfl_xor(dn, 8);
                if (lr == 0 && row < NN) {
                    ats_o[row * NH + h] = ds > 0.f ? ds : 0.2f * ds;
                    atn_o[row * NH + h] = dn > 0.f ? dn : 0.2f * dn;
                }
            }
        }
    }
}

// ---------------- fused gather pass A: GAT-L0 + 3x GCN-L0 ----------------

__global__ __launch_bounds__(256) void spmm_fusedA(
    const short* __restrict__ hnb, const short* __restrict__ fbf, const float* __restrict__ ats,
    const float* __restrict__ atn, const int4* __restrict__ ed, const int* __restrict__ row_ptr,
    float* __restrict__ aggG, short* __restrict__ zu, short* __restrict__ zp,
    short* __restrict__ zf, float* __restrict__ rs_all) {
    int r = __builtin_amdgcn_readfirstlane((blockIdx.x * 256 + threadIdx.x) >> 6);
    int lane = threadIdx.x & 63;
    if (r >= NN) return;
    int hh = lane >> 3;
    float a_s = ats[r * NH + hh];
    int start = row_ptr[r], end = row_ptr[r + 1];
    float2 ag = {0.f, 0.f}, au = {0.f, 0.f}, ap = {0.f, 0.f}, af2 = {0.f, 0.f};
    float su = 0.f, sp = 0.f, sf = 0.f;
    int j = start;
    for (; j + 2 <= end; j += 2) {
        int4 a0 = ed[2 * j], b0 = ed[2 * j + 1];
        int4 a1 = ed[2 * j + 2], b1 = ed[2 * j + 3];
        int cA = a0.x, cB = a1.x;
        float at0 = atn[cA * NH + hh], at1 = atn[cB * NH + hh];
        unsigned int g0 = *(const unsigned int*)(hnb + (size_t)cA * DD + lane * 2);
        unsigned int f0 = *(const unsigned int*)(fbf + (size_t)cA * DD + lane * 2);
        unsigned int g1 = *(const unsigned int*)(hnb + (size_t)cB * DD + lane * 2);
        unsigned int f1 = *(const unsigned int*)(fbf + (size_t)cB * DD + lane * 2);
        {
            float vg = __int_as_float(a0.y), vu = __int_as_float(a0.z);
            float vp = __int_as_float(a0.w), vf = __int_as_float(b0.x);
            float e = (a_s + at0) * vg;
            float glo = bflo(g0), ghi = bfhi(g0), flo = bflo(f0), fhi = bfhi(f0);
            ag.x += e * glo;  ag.y += e * ghi;
            au.x += vu * flo; au.y += vu * fhi;
            ap.x += vp * flo; ap.y += vp * fhi;
            af2.x += vf * flo; af2.y += vf * fhi;
            su += vu; sp += vp; sf += vf;
        }
        {
            float vg = __int_as_float(a1.y), vu = __int_as_float(a1.z);
            float vp = __int_as_float(a1.w), vf = __int_as_float(b1.x);
            float e = (a_s + at1) * vg;
            float glo = bflo(g1), ghi = bfhi(g1), flo = bflo(f1), fhi = bfhi(f1);
            ag.x += e * glo;  ag.y += e * ghi;
            au.x += vu * flo; au.y += vu * fhi;
            ap.x += vp * flo; ap.y += vp * fhi;
            af2.x += vf * flo; af2.y += vf * fhi;
            su += vu; sp += vp; sf += vf;
        }
    }
    if (j < end) {
        int4 a0 = ed[2 * j], b0 = ed[2 * j + 1];
        int cA = a0.x;
        float at0 = atn[cA * NH + hh];
        unsigned int g0 = *(const unsigned int*)(hnb + (size_t)cA * DD + lane * 2);
        unsigned int f0 = *(const unsigned int*)(fbf + (size_t)cA * DD + lane * 2);
        float vg = __int_as_float(a0.y), vu = __int_as_float(a0.z);
        float vp = __int_as_float(a0.w), vf = __int_as_float(b0.x);
        float e = (a_s + at0) * vg;
        float glo = bflo(g0), ghi = bfhi(g0), flo = bflo(f0), fhi = bfhi(f0);
        ag.x += e * glo;  ag.y += e * ghi;
        au.x += vu * flo; au.y += vu * fhi;
        ap.x += vp * flo; ap.y += vp * fhi;
        af2.x += vf * flo; af2.y += vf * fhi;
        su += vu; sp += vp; sf += vf;
    }
    size_t o = (size_t)r * DD + lane * 2;
    *(float2*)&aggG[o] = ag;
    *(unsigned int*)(zu + o) = pack2bf(au.x, au.y);
    *(unsigned int*)(zp + o) = pack2bf(ap.x, ap.y);
    *(unsigned int*)(zf + o) = pack2bf(af2.x, af2.y);
    if (lane == 0) {
        rs_all[r] = su;
        rs_all[NN + r] = sp;
        rs_all[2 * NN + r] = sf;
    }
}

// ---------------- GAT L1 gather (unroll 2) ----------------

__global__ __launch_bounds__(256) void spmm_gat_kernel(const short* __restrict__ hnb,
                                                       const float* __restrict__ ats,
                                                       const float* __restrict__ atn,
                                                       const int4* __restrict__ ed,
                                                       const int* __restrict__ row_ptr,
                                                       float* __restrict__ agg) {
    int r = __builtin_amdgcn_readfirstlane((blockIdx.x * 256 + threadIdx.x) >> 6);
    int lane = threadIdx.x & 63;
    if (r >= NN) return;
    int hh = lane >> 3;
    float a_s = ats[r * NH + hh];
    int start = row_ptr[r], end = row_ptr[r + 1];
    float2 acc = {0.f, 0.f};
    int j = start;
    for (; j + 2 <= end; j += 2) {
        int4 a0 = ed[2 * j];
        int4 a1 = ed[2 * j + 2];
        int cA = a0.x, cB = a1.x;
        float at0 = atn[cA * NH + hh], at1 = atn[cB * NH + hh];
        unsigned int g0 = *(const unsigned int*)(hnb + (size_t)cA * DD + lane * 2);
        unsigned int g1 = *(const unsigned int*)(hnb + (size_t)cB * DD + lane * 2);
        float e0 = (a_s + at0) * __int_as_float(a0.y);
        float e1 = (a_s + at1) * __int_as_float(a1.y);
        acc.x += e0 * bflo(g0) + e1 * bflo(g1);
        acc.y += e0 * bfhi(g0) + e1 * bfhi(g1);
    }
    if (j < end) {
        int4 a0 = ed[2 * j];
        int cA = a0.x;
        float at0 = atn[cA * NH + hh];
        unsigned int g0 = *(const unsigned int*)(hnb + (size_t)cA * DD + lane * 2);
        float e0 = (a_s + at0) * __int_as_float(a0.y);
        acc.x += e0 * bflo(g0);
        acc.y += e0 * bfhi(g0);
    }
    *(float2*)&agg[(size_t)r * DD + lane * 2] = acc;
}

// ---------------- fused gather pass C: 3x GCN-L1 ----------------

__global__ __launch_bounds__(256) void spmm_fusedC(const short* __restrict__ f1u,
                                                   const short* __restrict__ f1p,
                                                   const short* __restrict__ f1f,
                                                   const int4* __restrict__ ed,
                                                   const int* __restrict__ row_ptr,
                                                   short* __restrict__ z1u,
                                                   short* __restrict__ z1p,
                                                   short* __restrict__ z1f) {
    int r = __builtin_amdgcn_readfirstlane((blockIdx.x * 256 + threadIdx.x) >> 6);
    int lane = threadIdx.x & 63;
    if (r >= NN) return;
    int start = row_ptr[r], end = row_ptr[r + 1];
    float2 au = {0.f, 0.f}, ap = {0.f, 0.f}, af2 = {0.f, 0.f};
    int j = start;
    for (; j + 2 <= end; j += 2) {
        int4 a0 = ed[2 * j], b0 = ed[2 * j + 1];
        int4 a1 = ed[2 * j + 2], b1 = ed[2 * j + 3];
        int cA = a0.x, cB = a1.x;
        unsigned int u0 = *(const unsigned int*)(f1u + (size_t)cA * DD + lane * 2);
        unsigned int p0 = *(const unsigned int*)(f1p + (size_t)cA * DD + lane * 2);
        unsigned int q0 = *(const unsigned int*)(f1f + (size_t)cA * DD + lane * 2);
        unsigned int u1 = *(const unsigned int*)(f1u + (size_t)cB * DD + lane * 2);
        unsigned int p1 = *(const unsigned int*)(f1p + (size_t)cB * DD + lane * 2);
        unsigned int q1 = *(const unsigned int*)(f1f + (size_t)cB * DD + lane * 2);
        float vu0 = __int_as_float(a0.z), vp0 = __int_as_float(a0.w), vf0 = __int_as_float(b0.x);
        float vu1 = __int_as_float(a1.z), vp1 = __int_as_float(a1.w), vf1 = __int_as_float(b1.x);
        au.x += vu0 * bflo(u0) + vu1 * bflo(u1);
        au.y += vu0 * bfhi(u0) + vu1 * bfhi(u1);
        ap.x += vp0 * bflo(p0) + vp1 * bflo(p1);
        ap.y += vp0 * bfhi(p0) + vp1 * bfhi(p1);
        af2.x += vf0 * bflo(q0) + vf1 * bflo(q1);
        af2.y += vf0 * bfhi(q0) + vf1 * bfhi(q1);
    }
    if (j < end) {
        int4 a0 = ed[2 * j], b0 = ed[2 * j + 1];
        int cA = a0.x;
        unsigned int u0 = *(const unsigned int*)(f1u + (size_t)cA * DD + lane * 2);
        unsigned int p0 = *(const unsigned int*)(f1p + (size_t)cA * DD + lane * 2);
        unsigned int q0 = *(const unsigned int*)(f1f + (size_t)cA * DD + lane * 2);
        float vu0 = __int_as_float(a0.z), vp0 = __int_as_float(a0.w), vf0 = __int_as_float(b0.x);
        au.x += vu0 * bflo(u0);
        au.y += vu0 * bfhi(u0);
        ap.x += vp0 * bflo(p0);
        ap.y += vp0 * bfhi(p0);
        af2.x += vf0 * bflo(q0);
        af2.y += vf0 * bfhi(q0);
    }
    size_t o = (size_t)r * DD + lane * 2;
    *(unsigned int*)(z1u + o) = pack2bf(au.x, au.y);
    *(unsigned int*)(z1p + o) = pack2bf(ap.x, ap.y);
    *(unsigned int*)(z1f + o) = pack2bf(af2.x, af2.y);
}

// ---------------- BN stats (GAT agg) ----------------

__global__ __launch_bounds__(256) void bn_stats_kernel(const float* __restrict__ x,
                                                       float* __restrict__ stats) {
    int c = threadIdx.x & 127;
    int sub = threadIdx.x >> 7;
    int rows_per_block = (NN + gridDim.x - 1) / gridDim.x;
    int rbeg = blockIdx.x * rows_per_block;
    int rend = min(rbeg + rows_per_block, NN);
    float s = 0.f, q = 0.f;
    for (int r = rbeg + sub; r < rend; r += 2) {
        float v = x[(size_t)r * DD + c];
        s += v;
        q += v * v;
    }
    atomicAdd(&stats[c], s);
    atomicAdd(&stats[DD + c], q);
}

// ---------------- BN(relu(h)) -> bf16 ----------------

__global__ __launch_bounds__(256) void bnapply_bf16_kernel(const float* __restrict__ h,
                                                           const float* __restrict__ stats,
                                                           short* __restrict__ outb) {
    __shared__ float mS[DD], sS[DD];
    int t = threadIdx.x;
    if (t < DD) {
        const float inv_n = 1.0f / (float)NN;
        float m = stats[t] * inv_n;
        float var = stats[DD + t] * inv_n - m * m;
        mS[t] = m;
        sS[t] = rsqrtf(var + 1e-9f);
    }
    __syncthreads();
    int idx = blockIdx.x * 256 + t;
    if (idx >= NN * DD / 8) return;
    int c0 = (idx & 15) * 8;
    float4 a = ((const float4*)h)[idx * 2];
    float4 b = ((const float4*)h)[idx * 2 + 1];
    float vv[8] = {a.x, a.y, a.z, a.w, b.x, b.y, b.z, b.w};
#pragma unroll
    for (int e = 0; e < 8; ++e) vv[e] = (fmaxf(vv[e], 0.f) - mS[c0 + e]) * sS[c0 + e];
    uint4 o;
    o.x = pack2bf(vv[0], vv[1]);
    o.y = pack2bf(vv[2], vv[3]);
    o.z = pack2bf(vv[4], vv[5]);
    o.w = pack2bf(vv[6], vv[7]);
    *(uint4*)(outb + (size_t)idx * 8) = o;
}

// ---------------- classifier ----------------

template <int PRE, bool FIRST>
__global__ __launch_bounds__(256) void cls_acc_kernel(const float* __restrict__ o,
                                                      const float* __restrict__ Wc,
                                                      const float* __restrict__ stats,
                                                      const float* __restrict__ b_cls,
                                                      float* __restrict__ out) {
    __shared__ float Wl[DD * NCLS];
    __shared__ float mS[DD], sS[DD];
    int t = threadIdx.x;
    for (int i = t; i < DD * NCLS; i += 256) Wl[i] = Wc[i];
    if (PRE && t < DD) {
        const float inv_n = 1.0f / (float)NN;
        float m = stats[t] * inv_n;
        float var = stats[DD + t] * inv_n - m * m;
        mS[t] = m;
        sS[t] = rsqrtf(var + 1e-9f);
    }
    __syncthreads();
    int n = blockIdx.x * 256 + t;
    if (n >= NN) return;
    float acc[NCLS] = {};
    const float4* orow = (const float4*)(o + (size_t)n * DD);
    for (int k4 = 0; k4 < DD / 4; ++k4) {
        float4 v = orow[k4];
#pragma unroll
        for (int kk = 0; kk < 4; ++kk) {
            int k = k4 * 4 + kk;
            float a = ((const float*)&v)[kk];
            if (PRE == 2) a = fmaxf(a, 0.f);
            if (PRE) a = (a - mS[k]) * sS[k];
#pragma unroll
            for (int c = 0; c < NCLS; ++c) acc[c] += a * Wl[k * NCLS + c];
        }
    }
#pragma unroll
    for (int c = 0; c < NCLS; ++c) {
        if (FIRST)
            out[n * NCLS + c] = acc[c] + b_cls[c];
        else
            out[n * NCLS + c] += acc[c];
    }
}

// ---------------------------------------------------------------------------

extern "C" void kernel_launch(void* const* d_in, const int* in_sizes, int n_in, void* d_out,
                              int out_size, void* d_ws, size_t ws_size, hipStream_t stream) {
    const float* f_in = (const float*)d_in[0];
    const int* edge_row = (const int*)d_in[1];
    const int* edge_col = (const int*)d_in[2];
    const float* vals_gat = (const float*)d_in[3];
    const float* vals_uttr = (const float*)d_in[4];
    const float* vals_past = (const float*)d_in[5];
    const float* vals_futr = (const float*)d_in[6];
    const float* gat_Ws = (const float*)d_in[7];
    const float* gat_bs = (const float*)d_in[8];
    const float* gat_Wn = (const float*)d_in[9];
    const float* gat_bn = (const float*)d_in[10];
    const float* gat_as = (const float*)d_in[11];
    const float* gat_an = (const float*)d_in[12];
    const float* W_uttr = (const float*)d_in[13];
    const float* b_uttr = (const float*)d_in[14];
    const float* W_past = (const float*)d_in[15];
    const float* b_past = (const float*)d_in[16];
    const float* W_futr = (const float*)d_in[17];
    const float* b_futr = (const float*)d_in[18];
    const float* W_self = (const float*)d_in[19];
    const float* b_self = (const float*)d_in[20];
    const float* W_cls = (const float*)d_in[21];
    const float* b_cls = (const float*)d_in[22];
    float* out = (float*)d_out;

    char* ws = (char*)d_ws;
    size_t off = 0;
    auto alloc = [&](size_t bytes) -> void* {
        void* p = ws + off;
        off = (off + bytes + 255) & ~(size_t)255;
        return p;
    };
    float* stats_all = (float*)alloc(9 * 2 * DD * 4);
    int* cnt = (int*)alloc((size_t)NN * 4);  // adjacent -> one memset
    float* tmp1 = (float*)alloc((size_t)NN * DD * 4);  // GCN h0/h1, self h
    float* bufA = (float*)alloc((size_t)NN * DD * 4);  // GAT agg; later z1p/z1f
    short* fbf = (short*)alloc((size_t)NN * DD * 2);   // f_in bf16
    short* hnb = (short*)alloc((size_t)NN * DD * 2);   // GAT hn; later z1u
    short* z0u = (short*)alloc((size_t)NN * DD * 2);   // z0 -> f1 (reused)
    short* z0p = (short*)alloc((size_t)NN * DD * 2);
    short* z0f = (short*)alloc((size_t)NN * DD * 2);
    float* rs_all = (float*)alloc((size_t)3 * NN * 4);
    float* ats_b = (float*)alloc((size_t)NN * NH * 4);
    float* atn_b = (float*)alloc((size_t)NN * NH * 4);
    short* Wt_all = (short*)alloc((size_t)11 * DD * DD * 2);
    int* row_ptr = (int*)alloc((size_t)(NN + 1) * 4);
    int* fill = (int*)alloc((size_t)NN * 4);
    int* pre_b = (int*)alloc((size_t)NN * 4);
    int* bsum = (int*)alloc((size_t)SCAN_B * 4);
    int* boff = (int*)alloc((size_t)257 * 4);
    int4* ed = (int4*)alloc((size_t)NE * 32);

    auto stats = [&](int s) { return stats_all + (size_t)s * 2 * DD; };
    auto Wt = [&](int w) { return Wt_all + (size_t)w * DD * DD; };
    short* z0[3] = {z0u, z0p, z0f};
    short* z1[3] = {hnb, (short*)bufA, (short*)bufA + (size_t)NN * DD};

    const int gE = (NE + 255) / 256;
    const int gMM = (NN + 63) / 64;
    const int gSP = (NN + 3) / 4;
    const int gCA = (NN + 255) / 256;
    const int gBF = (NN * DD / 8 + 255) / 256;

    hipMemsetAsync(stats_all, 0, 9 * 2 * DD * 4 + (size_t)NN * 4, stream);

    // CSR build
    count_kernel<<<gE, 256, 0, stream>>>(edge_row, cnt);
    scan1_kernel<<<SCAN_B, 256, 0, stream>>>(cnt, pre_b, bsum);
    scan2_kernel<<<1, 256, 0, stream>>>(bsum, boff);
    scan3_kernel<<<SCAN_B, 256, 0, stream>>>(pre_b, boff, row_ptr, fill);
    scatter_kernel<<<gE, 256, 0, stream>>>(edge_row, edge_col, vals_gat, vals_uttr, vals_past,
                                           vals_futr, fill, ed);

    tobf16_kernel<<<gBF, 256, 0, stream>>>(f_in, fbf);

    WPrepArgs wa;
    wa.src[0] = gat_Ws;
    wa.src[1] = gat_Wn;
    wa.src[2] = gat_Ws + (size_t)DD * DD;
    wa.src[3] = gat_Wn + (size_t)DD * DD;
    wa.src[4] = W_uttr;
    wa.src[5] = W_uttr + (size_t)DD * DD;
    wa.src[6] = W_past;
    wa.src[7] = W_past + (size_t)DD * DD;
    wa.src[8] = W_futr;
    wa.src[9] = W_futr + (size_t)DD * DD;
    wa.src[10] = W_self;
    wprep_kernel<<<(11 * DD * DD + 255) / 256, 256, 0, stream>>>(wa, Wt_all);

    // ---- self branch (FIRST classifier write) ----
    mfma_mm<true, false, 1><<<gMM, 256, 0, stream>>>(fbf, Wt(10), b_self, nullptr, stats(8), tmp1);
    cls_acc_kernel<1, true><<<gCA, 256, 0, stream>>>(tmp1, W_cls + (size_t)4 * DD * NCLS,
                                                     stats(8), b_cls, out);

    // ---- GAT L0 + fused gather (also GCN L0 z) ----
    mfma_mm_pair<0><<<gMM, 256, 0, stream>>>(fbf, Wt(0), Wt(1), gat_bs, gat_bn, gat_as, gat_an,
                                             nullptr, hnb, ats_b, atn_b);
    spmm_fusedA<<<gSP, 256, 0, stream>>>(hnb, fbf, ats_b, atn_b, ed, row_ptr, bufA, z0u, z0p,
                                         z0f, rs_all);
    bn_stats_kernel<<<256, 256, 0, stream>>>(bufA, stats(0));
    // ---- GAT L1 ----
    mfma_mm_pair<1><<<gMM, 256, 0, stream>>>(bufA, Wt(2), Wt(3), gat_bs + DD, gat_bn + DD,
                                             gat_as + DD, gat_an + DD, stats(0), hnb, ats_b,
                                             atn_b);
    spmm_gat_kernel<<<gSP, 256, 0, stream>>>(hnb, ats_b, atn_b, ed, row_ptr, bufA);
    bn_stats_kernel<<<256, 256, 0, stream>>>(bufA, stats(1));
    cls_acc_kernel<1, false><<<gCA, 256, 0, stream>>>(bufA, W_cls, stats(1), b_cls, out);

    // ---- GCN L0 matmuls + BN->bf16 (f1 reuses z0 storage) ----
    const float* bb[3] = {b_uttr, b_past, b_futr};
    for (int br = 0; br < 3; ++br) {
        int w0 = 4 + br * 2;
        int s0 = 2 + br * 2;
        mfma_mm<false, true, 2><<<gMM, 256, 0, stream>>>(z0[br], Wt(w0), bb[br],
                                                         rs_all + (size_t)br * NN, stats(s0),
                                                         tmp1);
        bnapply_bf16_kernel<<<gBF, 256, 0, stream>>>(tmp1, stats(s0), z0[br]);
    }
    // ---- fused GCN L1 gather ----
    spmm_fusedC<<<gSP, 256, 0, stream>>>(z0u, z0p, z0f, ed, row_ptr, z1[0], z1[1], z1[2]);
    // ---- GCN L1 matmuls + classifier ----
    for (int br = 0; br < 3; ++br) {
        int w0 = 4 + br * 2;
        int s0 = 2 + br * 2;
        mfma_mm<false, true, 2><<<gMM, 256, 0, stream>>>(z1[br], Wt(w0 + 1), bb[br] + DD,
                                                         rs_all + (size_t)br * NN, stats(s0 + 1),
                                                         tmp1);
        cls_acc_kernel<2, false><<<gCA, 256, 0, stream>>>(
            tmp1, W_cls + (size_t)(DD + DD * br) * NCLS, stats(s0 + 1), b_cls, out);
    }
}

// Round 5
// 572.845 us; speedup vs baseline: 2.6025x; 1.1600x over previous
//
#include <hip/hip_runtime.h>
#include <hip/hip_bf16.h>

// ---------------------------------------------------------------------------
// ERCGNN R5: 2 fused gather passes total (A: GAT-L0+3xGCN-L0; B: GAT-L1+
// 3xGCN-L1), BN folded into L1 weights (wfix), bnapply passes eliminated,
// batched GCN matmuls, bf16 classifier inputs for GCN.
// ---------------------------------------------------------------------------

#define NN 50000
#define NE 500000
#define DD 128
#define NH 8
#define DHD 16
#define NCLS 7
#define SCAN_B 196  // ceil(50000/256)

typedef __attribute__((ext_vector_type(8))) short short8;
typedef __attribute__((ext_vector_type(4))) float f32x4;

__device__ __forceinline__ unsigned short f2bf(float x) {
    unsigned int u = __float_as_uint(x);
    unsigned int r = (u + 0x7fffu + ((u >> 16) & 1u)) >> 16;  // RNE
    return (unsigned short)r;
}
__device__ __forceinline__ unsigned int pack2bf(float lo, float hi) {
    return (unsigned int)f2bf(lo) | ((unsigned int)f2bf(hi) << 16);
}
__device__ __forceinline__ float bflo(unsigned int u) { return __uint_as_float(u << 16); }
__device__ __forceinline__ float bfhi(unsigned int u) { return __uint_as_float(u & 0xffff0000u); }

// ---------------- CSR build ----------------

__global__ void count_kernel(const int* __restrict__ row, int* __restrict__ cnt) {
    int e = blockIdx.x * 256 + threadIdx.x;
    if (e < NE) atomicAdd(&cnt[row[e]], 1);
}

__global__ __launch_bounds__(256) void scan1_kernel(const int* __restrict__ cnt,
                                                    int* __restrict__ pre,
                                                    int* __restrict__ bsum) {
    __shared__ int s[256];
    int t = threadIdx.x;
    int i = blockIdx.x * 256 + t;
    int v = (i < NN) ? cnt[i] : 0;
    s[t] = v;
    __syncthreads();
    for (int off = 1; off < 256; off <<= 1) {
        int u = (t >= off) ? s[t - off] : 0;
        __syncthreads();
        s[t] += u;
        __syncthreads();
    }
    if (i < NN) pre[i] = s[t] - v;
    if (t == 255) bsum[blockIdx.x] = s[255];
}

__global__ __launch_bounds__(256) void scan2_kernel(const int* __restrict__ bsum,
                                                    int* __restrict__ boff) {
    __shared__ int s[256];
    int t = threadIdx.x;
    int v = (t < SCAN_B) ? bsum[t] : 0;
    s[t] = v;
    __syncthreads();
    for (int off = 1; off < 256; off <<= 1) {
        int u = (t >= off) ? s[t - off] : 0;
        __syncthreads();
        s[t] += u;
        __syncthreads();
    }
    boff[t] = s[t] - v;
    if (t == 255) boff[256] = s[255];
}

__global__ __launch_bounds__(256) void scan3_kernel(const int* __restrict__ pre,
                                                    const int* __restrict__ boff,
                                                    int* __restrict__ row_ptr,
                                                    int* __restrict__ fill) {
    int t = threadIdx.x;
    int i = blockIdx.x * 256 + t;
    if (i < NN) {
        int v = pre[i] + boff[blockIdx.x];
        row_ptr[i] = v;
        fill[i] = v;
    }
    if (blockIdx.x == 0 && t == 0) row_ptr[NN] = boff[256];
}

// 32B edge record: {col, vg, vu, vp} {vf, 0, 0, 0}
__global__ void scatter_kernel(const int* __restrict__ row, const int* __restrict__ col,
                               const float* __restrict__ vg, const float* __restrict__ vu,
                               const float* __restrict__ vp, const float* __restrict__ vf,
                               int* __restrict__ fill, int4* __restrict__ ed) {
    int e = blockIdx.x * 256 + threadIdx.x;
    if (e >= NE) return;
    int r = row[e];
    int pos = atomicAdd(&fill[r], 1);
    ed[2 * pos] = make_int4(col[e], __float_as_int(vg[e]), __float_as_int(vu[e]),
                            __float_as_int(vp[e]));
    ed[2 * pos + 1] = make_int4(__float_as_int(vf[e]), 0, 0, 0);
}

// ---------------- fp32 -> bf16 copy ----------------

__global__ __launch_bounds__(256) void tobf16_kernel(const float* __restrict__ x,
                                                     short* __restrict__ y) {
    int idx = blockIdx.x * 256 + threadIdx.x;
    if (idx >= NN * DD / 8) return;
    float4 a = ((const float4*)x)[idx * 2];
    float4 b = ((const float4*)x)[idx * 2 + 1];
    uint4 o;
    o.x = pack2bf(a.x, a.y);
    o.y = pack2bf(a.z, a.w);
    o.z = pack2bf(b.x, b.y);
    o.w = pack2bf(b.z, b.w);
    *(uint4*)(y + (size_t)idx * 8) = o;
}

// ---------------- weight prep ----------------

struct WPrepArgs {
    const float* src[11];
};

__global__ __launch_bounds__(256) void wprep_kernel(WPrepArgs a, short* __restrict__ out) {
    int idx = blockIdx.x * 256 + threadIdx.x;
    if (idx >= 11 * DD * DD) return;
    int w = idx >> 14;
    int r = idx & 16383;
    int n = r >> 7, k = r & 127;
    const float* W = a.src[w];
    float v = (w < 4) ? W[(size_t)((n >> 4) * DD + k) * DHD + (n & 15)] : W[(size_t)k * DD + n];
    out[idx] = (short)f2bf(v);
}

// ---- wfix: fold BN(y0) into L1 weights. Wt'[n][k]=s[k]*W1[k][n] (bf16,
// col-major), bfix[n] = b1[n] - sum_k m[k]*s[k]*W1[k][n] ----

struct WFixArgs {
    const float* W1[3];    // original fp32 [128][128]
    const float* b1[3];
    const float* stats[3]; // y0 stats slices
};

__global__ __launch_bounds__(256) void wfix_kernel(WFixArgs a, short* __restrict__ wt_out,
                                                   float* __restrict__ bfix) {
    int idx = blockIdx.x * 256 + threadIdx.x;
    if (idx >= 3 * DD) return;
    int br = idx >> 7, n = idx & 127;
    const float* st = a.stats[br];
    const float* W = a.W1[br];
    const float inv_n = 1.0f / (float)NN;
    float accb = 0.f;
    short* wo = wt_out + (size_t)br * DD * DD + (size_t)n * DD;
#pragma unroll 4
    for (int k = 0; k < DD; ++k) {
        float m = st[k] * inv_n;
        float var = st[DD + k] * inv_n - m * m;
        float s = rsqrtf(var + 1e-9f);
        float w = W[(size_t)k * DD + n];
        wo[k] = (short)f2bf(s * w);
        accb += m * s * w;
    }
    bfix[idx] = a.b1[br][n] - accb;
}

// ---------------- MFMA matmul core (macro-ish via template) ----------------
// Self branch: bf16 A, fp32 C (relu), stats of stored.

__global__ __launch_bounds__(256) void mfma_mm_self(const short* __restrict__ A,
                                                    const short* __restrict__ Wt,
                                                    const float* __restrict__ bias,
                                                    float* __restrict__ stats_out,
                                                    float* __restrict__ C) {
    __shared__ short As[64 * DD];
    int t = threadIdx.x;
    int r0 = blockIdx.x * 64;
    {
        int srow = t >> 2;
        int sk0 = (t & 3) * 32;
        int grow = r0 + srow;
#pragma unroll
        for (int j = 0; j < 4; ++j) {
            int k0 = sk0 + j * 8;
            short8 frag = {0, 0, 0, 0, 0, 0, 0, 0};
            if (grow < NN) frag = *(const short8*)(A + (size_t)grow * DD + k0);
            int byte = srow * 256 + k0 * 2;
            byte ^= (srow & 7) << 4;
            *(short8*)((char*)As + byte) = frag;
        }
    }
    __syncthreads();
    int w = t >> 6, l = t & 63;
    int c0 = w * 32;
    int lr = l & 15, lg = l >> 4;
    f32x4 acc[4][2] = {};
#pragma unroll
    for (int s = 0; s < 4; ++s) {
        short8 af[4];
#pragma unroll
        for (int f = 0; f < 4; ++f) {
            int rr = f * 16 + lr;
            int byte = rr * 256 + (s * 32 + lg * 8) * 2;
            byte ^= (rr & 7) << 4;
            af[f] = *(const short8*)((const char*)As + byte);
        }
#pragma unroll
        for (int g = 0; g < 2; ++g) {
            int col = c0 + g * 16 + lr;
            short8 bf = *(const short8*)&Wt[(size_t)col * DD + s * 32 + lg * 8];
#pragma unroll
            for (int f = 0; f < 4; ++f)
                acc[f][g] = __builtin_amdgcn_mfma_f32_16x16x32_bf16(af[f], bf, acc[f][g], 0, 0, 0);
        }
    }
    float sA[2] = {0.f, 0.f}, qA[2] = {0.f, 0.f};
#pragma unroll
    for (int g = 0; g < 2; ++g) {
        int col = c0 + g * 16 + lr;
        float b = bias[col];
#pragma unroll
        for (int f = 0; f < 4; ++f)
#pragma unroll
            for (int i = 0; i < 4; ++i) {
                int row = r0 + f * 16 + lg * 4 + i;
                if (row < NN) {
                    float o = fmaxf(acc[f][g][i] + b, 0.f);
                    C[(size_t)row * DD + col] = o;
                    sA[g] += o;
                    qA[g] += o * o;
                }
            }
    }
#pragma unroll
    for (int g = 0; g < 2; ++g) {
        sA[g] += __shfl_xor(sA[g], 16);
        sA[g] += __shfl_xor(sA[g], 32);
        qA[g] += __shfl_xor(qA[g], 16);
        qA[g] += __shfl_xor(qA[g], 32);
    }
    if (lg == 0)
#pragma unroll
        for (int g = 0; g < 2; ++g) {
            int col = c0 + g * 16 + lr;
            atomicAdd(&stats_out[col], sA[g]);
            atomicAdd(&stats_out[DD + col], qA[g]);
        }
}

// ---- batched GCN matmul: y[br] = relu(A[br]@W[br] + rs[br]*bias[br]) -> bf16
// stats of y (pre-rounding fp32). In-place A==C allowed (LDS staging barrier).

struct MMB {
    const short* A[3];
    const short* W[3];
    const float* bias[3];
    const float* rs[3];
    float* stats[3];
    short* C[3];
};

__global__ __launch_bounds__(256) void mfma_mm_gcn(MMB m) {
    int br = blockIdx.y;
    const short* A = m.A[br];
    const short* Wt = m.W[br];
    const float* bias = m.bias[br];
    const float* rs = m.rs[br];
    float* stats_out = m.stats[br];
    short* C = m.C[br];

    __shared__ short As[64 * DD];
    int t = threadIdx.x;
    int r0 = blockIdx.x * 64;
    {
        int srow = t >> 2;
        int sk0 = (t & 3) * 32;
        int grow = r0 + srow;
#pragma unroll
        for (int j = 0; j < 4; ++j) {
            int k0 = sk0 + j * 8;
            short8 frag = {0, 0, 0, 0, 0, 0, 0, 0};
            if (grow < NN) frag = *(const short8*)(A + (size_t)grow * DD + k0);
            int byte = srow * 256 + k0 * 2;
            byte ^= (srow & 7) << 4;
            *(short8*)((char*)As + byte) = frag;
        }
    }
    __syncthreads();
    int w = t >> 6, l = t & 63;
    int c0 = w * 32;
    int lr = l & 15, lg = l >> 4;
    f32x4 acc[4][2] = {};
#pragma unroll
    for (int s = 0; s < 4; ++s) {
        short8 af[4];
#pragma unroll
        for (int f = 0; f < 4; ++f) {
            int rr = f * 16 + lr;
            int byte = rr * 256 + (s * 32 + lg * 8) * 2;
            byte ^= (rr & 7) << 4;
            af[f] = *(const short8*)((const char*)As + byte);
        }
#pragma unroll
        for (int g = 0; g < 2; ++g) {
            int col = c0 + g * 16 + lr;
            short8 bf = *(const short8*)&Wt[(size_t)col * DD + s * 32 + lg * 8];
#pragma unroll
            for (int f = 0; f < 4; ++f)
                acc[f][g] = __builtin_amdgcn_mfma_f32_16x16x32_bf16(af[f], bf, acc[f][g], 0, 0, 0);
        }
    }
    float rsv[4][4];
#pragma unroll
    for (int f = 0; f < 4; ++f)
#pragma unroll
        for (int i = 0; i < 4; ++i) {
            int row = r0 + f * 16 + lg * 4 + i;
            rsv[f][i] = (row < NN) ? rs[row] : 0.f;
        }
    float sA[2] = {0.f, 0.f}, qA[2] = {0.f, 0.f};
#pragma unroll
    for (int g = 0; g < 2; ++g) {
        int col = c0 + g * 16 + lr;
        float b = bias[col];
#pragma unroll
        for (int f = 0; f < 4; ++f)
#pragma unroll
            for (int i = 0; i < 4; ++i) {
                int row = r0 + f * 16 + lg * 4 + i;
                if (row < NN) {
                    float o = fmaxf(acc[f][g][i] + rsv[f][i] * b, 0.f);
                    C[(size_t)row * DD + col] = (short)f2bf(o);
                    sA[g] += o;
                    qA[g] += o * o;
                }
            }
    }
#pragma unroll
    for (int g = 0; g < 2; ++g) {
        sA[g] += __shfl_xor(sA[g], 16);
        sA[g] += __shfl_xor(sA[g], 32);
        qA[g] += __shfl_xor(qA[g], 16);
        qA[g] += __shfl_xor(qA[g], 32);
    }
    if (lg == 0)
#pragma unroll
        for (int g = 0; g < 2; ++g) {
            int col = c0 + g * 16 + lr;
            atomicAdd(&stats_out[col], sA[g]);
            atomicAdd(&stats_out[DD + col], qA[g]);
        }
}

// ---- GAT pair matmul with fused attention ----
// PRE: 0 = A bf16; 1 = A fp32 with BN(stats_in).

template <int PRE>
__global__ __launch_bounds__(256) void mfma_mm_pair(const void* __restrict__ Av,
                                                    const short* __restrict__ Wt1,
                                                    const short* __restrict__ Wt2,
                                                    const float* __restrict__ b1,
                                                    const float* __restrict__ b2,
                                                    const float* __restrict__ a_se,
                                                    const float* __restrict__ a_ne,
                                                    const float* __restrict__ stats_in,
                                                    short* __restrict__ out2,
                                                    float* __restrict__ ats_o,
                                                    float* __restrict__ atn_o) {
    __shared__ short As[64 * DD];
    __shared__ float mS[DD], sS[DD];
    int t = threadIdx.x;
    int r0 = blockIdx.x * 64;
    if (PRE == 1) {
        if (t < DD) {
            const float inv_n = 1.0f / (float)NN;
            float m = stats_in[t] * inv_n;
            float var = stats_in[DD + t] * inv_n - m * m;
            mS[t] = m;
            sS[t] = rsqrtf(var + 1e-9f);
        }
        __syncthreads();
    }
    {
        int srow = t >> 2;
        int sk0 = (t & 3) * 32;
        int grow = r0 + srow;
#pragma unroll
        for (int j = 0; j < 4; ++j) {
            int k0 = sk0 + j * 8;
            short8 frag = {0, 0, 0, 0, 0, 0, 0, 0};
            if (grow < NN) {
                if (PRE == 0) {
                    frag = *(const short8*)((const short*)Av + (size_t)grow * DD + k0);
                } else {
                    const float* Ar = (const float*)Av + (size_t)grow * DD;
                    float4 v0 = *(const float4*)(Ar + k0);
                    float4 v1 = *(const float4*)(Ar + k0 + 4);
                    float vv[8] = {v0.x, v0.y, v0.z, v0.w, v1.x, v1.y, v1.z, v1.w};
#pragma unroll
                    for (int e = 0; e < 8; ++e)
                        frag[e] = (short)f2bf((vv[e] - mS[k0 + e]) * sS[k0 + e]);
                }
            }
            int byte = srow * 256 + k0 * 2;
            byte ^= (srow & 7) << 4;
            *(short8*)((char*)As + byte) = frag;
        }
    }
    __syncthreads();
    int w = t >> 6, l = t & 63;
    int c0 = w * 32;
    int lr = l & 15, lg = l >> 4;
    f32x4 acc1[4][2] = {}, acc2[4][2] = {};
#pragma unroll
    for (int s = 0; s < 4; ++s) {
        short8 af[4];
#pragma unroll
        for (int f = 0; f < 4; ++f) {
            int rr = f * 16 + lr;
            int byte = rr * 256 + (s * 32 + lg * 8) * 2;
            byte ^= (rr & 7) << 4;
            af[f] = *(const short8*)((const char*)As + byte);
        }
#pragma unroll
        for (int g = 0; g < 2; ++g) {
            int col = c0 + g * 16 + lr;
            short8 bfa = *(const short8*)&Wt1[(size_t)col * DD + s * 32 + lg * 8];
            short8 bfb = *(const short8*)&Wt2[(size_t)col * DD + s * 32 + lg * 8];
#pragma unroll
            for (int f = 0; f < 4; ++f) {
                acc1[f][g] = __builtin_amdgcn_mfma_f32_16x16x32_bf16(af[f], bfa, acc1[f][g], 0, 0, 0);
                acc2[f][g] = __builtin_amdgcn_mfma_f32_16x16x32_bf16(af[f], bfb, acc2[f][g], 0, 0, 0);
            }
        }
    }
#pragma unroll
    for (int g = 0; g < 2; ++g) {
        int colc = c0 + g * 16 + lr;
        float bb1 = b1[colc], bb2 = b2[colc];
        float asv = a_se[colc], anv = a_ne[colc];
        int h = (c0 >> 4) + g;
#pragma unroll
        for (int f = 0; f < 4; ++f)
#pragma unroll
            for (int i = 0; i < 4; ++i) {
                int row = r0 + f * 16 + lg * 4 + i;
                float o1 = fmaxf(acc1[f][g][i] + bb1, 0.f);  // hs (ephemeral)
                float o2 = fmaxf(acc2[f][g][i] + bb2, 0.f);  // hn
                if (row < NN) out2[(size_t)row * DD + colc] = (short)f2bf(o2);
                float ds = o1 * asv, dn = o1 * anv;
                ds += __shfl_xor(ds, 1);
                dn += __shfl_xor(dn, 1);
                ds += __shfl_xor(ds, 2);
                dn += __shfl_xor(dn, 2);
                ds += __shfl_xor(ds, 4);
                dn += __shfl_xor(dn, 4);
                ds += __shfl_xor(ds, 8);
                dn += __shfl_xor(dn, 8);
                if (lr == 0 && row < NN) {
                    ats_o[row * NH + h] = ds > 0.f ? ds : 0.2f * ds;
                    atn_o[row * NH + h] = dn > 0.f ? dn : 0.2f * dn;
                }
            }
    }
}

// ---------------- fused gather pass A: GAT-L0 + 3x GCN-L0 ----------------

__global__ __launch_bounds__(256) void spmm_fusedA(
    const short* __restrict__ hnb, const short* __restrict__ fbf, const float* __restrict__ ats,
    const float* __restrict__ atn, const int4* __restrict__ ed, const int* __restrict__ row_ptr,
    float* __restrict__ aggG, short* __restrict__ zu, short* __restrict__ zp,
    short* __restrict__ zf, float* __restrict__ rs_all) {
    int r = __builtin_amdgcn_readfirstlane((blockIdx.x * 256 + threadIdx.x) >> 6);
    int lane = threadIdx.x & 63;
    if (r >= NN) return;
    int hh = lane >> 3;
    float a_s = ats[r * NH + hh];
    int start = row_ptr[r], end = row_ptr[r + 1];
    float2 ag = {0.f, 0.f}, au = {0.f, 0.f}, ap = {0.f, 0.f}, af2 = {0.f, 0.f};
    float su = 0.f, sp = 0.f, sf = 0.f;
    int j = start;
    for (; j + 2 <= end; j += 2) {
        int4 a0 = ed[2 * j], b0 = ed[2 * j + 1];
        int4 a1 = ed[2 * j + 2], b1 = ed[2 * j + 3];
        int cA = a0.x, cB = a1.x;
        float at0 = atn[cA * NH + hh], at1 = atn[cB * NH + hh];
        unsigned int g0 = *(const unsigned int*)(hnb + (size_t)cA * DD + lane * 2);
        unsigned int f0 = *(const unsigned int*)(fbf + (size_t)cA * DD + lane * 2);
        unsigned int g1 = *(const unsigned int*)(hnb + (size_t)cB * DD + lane * 2);
        unsigned int f1 = *(const unsigned int*)(fbf + (size_t)cB * DD + lane * 2);
        {
            float vg = __int_as_float(a0.y), vu = __int_as_float(a0.z);
            float vp = __int_as_float(a0.w), vf = __int_as_float(b0.x);
            float e = (a_s + at0) * vg;
            float glo = bflo(g0), ghi = bfhi(g0), flo = bflo(f0), fhi = bfhi(f0);
            ag.x += e * glo;  ag.y += e * ghi;
            au.x += vu * flo; au.y += vu * fhi;
            ap.x += vp * flo; ap.y += vp * fhi;
            af2.x += vf * flo; af2.y += vf * fhi;
            su += vu; sp += vp; sf += vf;
        }
        {
            float vg = __int_as_float(a1.y), vu = __int_as_float(a1.z);
            float vp = __int_as_float(a1.w), vf = __int_as_float(b1.x);
            float e = (a_s + at1) * vg;
            float glo = bflo(g1), ghi = bfhi(g1), flo = bflo(f1), fhi = bfhi(f1);
            ag.x += e * glo;  ag.y += e * ghi;
            au.x += vu * flo; au.y += vu * fhi;
            ap.x += vp * flo; ap.y += vp * fhi;
            af2.x += vf * flo; af2.y += vf * fhi;
            su += vu; sp += vp; sf += vf;
        }
    }
    if (j < end) {
        int4 a0 = ed[2 * j], b0 = ed[2 * j + 1];
        int cA = a0.x;
        float at0 = atn[cA * NH + hh];
        unsigned int g0 = *(const unsigned int*)(hnb + (size_t)cA * DD + lane * 2);
        unsigned int f0 = *(const unsigned int*)(fbf + (size_t)cA * DD + lane * 2);
        float vg = __int_as_float(a0.y), vu = __int_as_float(a0.z);
        float vp = __int_as_float(a0.w), vf = __int_as_float(b0.x);
        float e = (a_s + at0) * vg;
        float glo = bflo(g0), ghi = bfhi(g0), flo = bflo(f0), fhi = bfhi(f0);
        ag.x += e * glo;  ag.y += e * ghi;
        au.x += vu * flo; au.y += vu * fhi;
        ap.x += vp * flo; ap.y += vp * fhi;
        af2.x += vf * flo; af2.y += vf * fhi;
        su += vu; sp += vp; sf += vf;
    }
    size_t o = (size_t)r * DD + lane * 2;
    *(float2*)&aggG[o] = ag;
    *(unsigned int*)(zu + o) = pack2bf(au.x, au.y);
    *(unsigned int*)(zp + o) = pack2bf(ap.x, ap.y);
    *(unsigned int*)(zf + o) = pack2bf(af2.x, af2.y);
    if (lane == 0) {
        rs_all[r] = su;
        rs_all[NN + r] = sp;
        rs_all[2 * NN + r] = sf;
    }
}

// ---------------- fused gather pass B: GAT-L1 + 3x GCN-L1 ----------------

__global__ __launch_bounds__(256) void spmm_fusedB(
    const short* __restrict__ hnb, const short* __restrict__ y0u, const short* __restrict__ y0p,
    const short* __restrict__ y0f, const float* __restrict__ ats, const float* __restrict__ atn,
    const int4* __restrict__ ed, const int* __restrict__ row_ptr, float* __restrict__ aggG,
    short* __restrict__ z1u, short* __restrict__ z1p, short* __restrict__ z1f) {
    int r = __builtin_amdgcn_readfirstlane((blockIdx.x * 256 + threadIdx.x) >> 6);
    int lane = threadIdx.x & 63;
    if (r >= NN) return;
    int hh = lane >> 3;
    float a_s = ats[r * NH + hh];
    int start = row_ptr[r], end = row_ptr[r + 1];
    float2 ag = {0.f, 0.f}, au = {0.f, 0.f}, ap = {0.f, 0.f}, af2 = {0.f, 0.f};
    int j = start;
    for (; j + 2 <= end; j += 2) {
        int4 a0 = ed[2 * j], b0 = ed[2 * j + 1];
        int4 a1 = ed[2 * j + 2], b1 = ed[2 * j + 3];
        int cA = a0.x, cB = a1.x;
        float at0 = atn[cA * NH + hh], at1 = atn[cB * NH + hh];
        size_t oA = (size_t)cA * DD + lane * 2, oB = (size_t)cB * DD + lane * 2;
        unsigned int g0 = *(const unsigned int*)(hnb + oA);
        unsigned int u0 = *(const unsigned int*)(y0u + oA);
        unsigned int p0 = *(const unsigned int*)(y0p + oA);
        unsigned int q0 = *(const unsigned int*)(y0f + oA);
        unsigned int g1 = *(const unsigned int*)(hnb + oB);
        unsigned int u1 = *(const unsigned int*)(y0u + oB);
        unsigned int p1 = *(const unsigned int*)(y0p + oB);
        unsigned int q1 = *(const unsigned int*)(y0f + oB);
        float e0 = (a_s + at0) * __int_as_float(a0.y);
        float e1 = (a_s + at1) * __int_as_float(a1.y);
        float vu0 = __int_as_float(a0.z), vp0 = __int_as_float(a0.w), vf0 = __int_as_float(b0.x);
        float vu1 = __int_as_float(a1.z), vp1 = __int_as_float(a1.w), vf1 = __int_as_float(b1.x);
        ag.x += e0 * bflo(g0) + e1 * bflo(g1);
        ag.y += e0 * bfhi(g0) + e1 * bfhi(g1);
        au.x += vu0 * bflo(u0) + vu1 * bflo(u1);
        au.y += vu0 * bfhi(u0) + vu1 * bfhi(u1);
        ap.x += vp0 * bflo(p0) + vp1 * bflo(p1);
        ap.y += vp0 * bfhi(p0) + vp1 * bfhi(p1);
        af2.x += vf0 * bflo(q0) + vf1 * bflo(q1);
        af2.y += vf0 * bfhi(q0) + vf1 * bfhi(q1);
    }
    if (j < end) {
        int4 a0 = ed[2 * j], b0 = ed[2 * j + 1];
        int cA = a0.x;
        float at0 = atn[cA * NH + hh];
        size_t oA = (size_t)cA * DD + lane * 2;
        unsigned int g0 = *(const unsigned int*)(hnb + oA);
        unsigned int u0 = *(const unsigned int*)(y0u + oA);
        unsigned int p0 = *(const unsigned int*)(y0p + oA);
        unsigned int q0 = *(const unsigned int*)(y0f + oA);
        float e0 = (a_s + at0) * __int_as_float(a0.y);
        float vu0 = __int_as_float(a0.z), vp0 = __int_as_float(a0.w), vf0 = __int_as_float(b0.x);
        ag.x += e0 * bflo(g0);
        ag.y += e0 * bfhi(g0);
        au.x += vu0 * bflo(u0);
        au.y += vu0 * bfhi(u0);
        ap.x += vp0 * bflo(p0);
        ap.y += vp0 * bfhi(p0);
        af2.x += vf0 * bflo(q0);
        af2.y += vf0 * bfhi(q0);
    }
    size_t o = (size_t)r * DD + lane * 2;
    *(float2*)&aggG[o] = ag;
    *(unsigned int*)(z1u + o) = pack2bf(au.x, au.y);
    *(unsigned int*)(z1p + o) = pack2bf(ap.x, ap.y);
    *(unsigned int*)(z1f + o) = pack2bf(af2.x, af2.y);
}

// ---------------- BN stats (GAT agg) ----------------

__global__ __launch_bounds__(256) void bn_stats_kernel(const float* __restrict__ x,
                                                       float* __restrict__ stats) {
    int c = threadIdx.x & 127;
    int sub = threadIdx.x >> 7;
    int rows_per_block = (NN + gridDim.x - 1) / gridDim.x;
    int rbeg = blockIdx.x * rows_per_block;
    int rend = min(rbeg + rows_per_block, NN);
    float s = 0.f, q = 0.f;
    for (int r = rbeg + sub; r < rend; r += 2) {
        float v = x[(size_t)r * DD + c];
        s += v;
        q += v * v;
    }
    atomicAdd(&stats[c], s);
    atomicAdd(&stats[DD + c], q);
}

// ---------------- classifier ----------------
// BF16IN: o is bf16 (already relu'd), PRE=1 only applies BN.

template <int PRE, bool FIRST, bool BF16IN>
__global__ __launch_bounds__(256) void cls_acc_kernel(const void* __restrict__ ov,
                                                      const float* __restrict__ Wc,
                                                      const float* __restrict__ stats,
                                                      const float* __restrict__ b_cls,
                                                      float* __restrict__ out) {
    __shared__ float Wl[DD * NCLS];
    __shared__ float mS[DD], sS[DD];
    int t = threadIdx.x;
    for (int i = t; i < DD * NCLS; i += 256) Wl[i] = Wc[i];
    if (PRE && t < DD) {
        const float inv_n = 1.0f / (float)NN;
        float m = stats[t] * inv_n;
        float var = stats[DD + t] * inv_n - m * m;
        mS[t] = m;
        sS[t] = rsqrtf(var + 1e-9f);
    }
    __syncthreads();
    int n = blockIdx.x * 256 + t;
    if (n >= NN) return;
    float acc[NCLS] = {};
    if (BF16IN) {
        const uint4* orow = (const uint4*)((const short*)ov + (size_t)n * DD);
        for (int k8 = 0; k8 < DD / 8; ++k8) {
            uint4 v = orow[k8];
            float vv[8] = {bflo(v.x), bfhi(v.x), bflo(v.y), bfhi(v.y),
                           bflo(v.z), bfhi(v.z), bflo(v.w), bfhi(v.w)};
#pragma unroll
            for (int kk = 0; kk < 8; ++kk) {
                int k = k8 * 8 + kk;
                float a = vv[kk];
                if (PRE == 2) a = fmaxf(a, 0.f);
                if (PRE) a = (a - mS[k]) * sS[k];
#pragma unroll
                for (int c = 0; c < NCLS; ++c) acc[c] += a * Wl[k * NCLS + c];
            }
        }
    } else {
        const float4* orow = (const float4*)((const float*)ov + (size_t)n * DD);
        for (int k4 = 0; k4 < DD / 4; ++k4) {
            float4 v = orow[k4];
#pragma unroll
            for (int kk = 0; kk < 4; ++kk) {
                int k = k4 * 4 + kk;
                float a = ((const float*)&v)[kk];
                if (PRE == 2) a = fmaxf(a, 0.f);
                if (PRE) a = (a - mS[k]) * sS[k];
#pragma unroll
                for (int c = 0; c < NCLS; ++c) acc[c] += a * Wl[k * NCLS + c];
            }
        }
    }
#pragma unroll
    for (int c = 0; c < NCLS; ++c) {
        if (FIRST)
            out[n * NCLS + c] = acc[c] + b_cls[c];
        else
            out[n * NCLS + c] += acc[c];
    }
}

// ---------------------------------------------------------------------------

extern "C" void kernel_launch(void* const* d_in, const int* in_sizes, int n_in, void* d_out,
                              int out_size, void* d_ws, size_t ws_size, hipStream_t stream) {
    const float* f_in = (const float*)d_in[0];
    const int* edge_row = (const int*)d_in[1];
    const int* edge_col = (const int*)d_in[2];
    const float* vals_gat = (const float*)d_in[3];
    const float* vals_uttr = (const float*)d_in[4];
    const float* vals_past = (const float*)d_in[5];
    const float* vals_futr = (const float*)d_in[6];
    const float* gat_Ws = (const float*)d_in[7];
    const float* gat_bs = (const float*)d_in[8];
    const float* gat_Wn = (const float*)d_in[9];
    const float* gat_bn = (const float*)d_in[10];
    const float* gat_as = (const float*)d_in[11];
    const float* gat_an = (const float*)d_in[12];
    const float* W_uttr = (const float*)d_in[13];
    const float* b_uttr = (const float*)d_in[14];
    const float* W_past = (const float*)d_in[15];
    const float* b_past = (const float*)d_in[16];
    const float* W_futr = (const float*)d_in[17];
    const float* b_futr = (const float*)d_in[18];
    const float* W_self = (const float*)d_in[19];
    const float* b_self = (const float*)d_in[20];
    const float* W_cls = (const float*)d_in[21];
    const float* b_cls = (const float*)d_in[22];
    float* out = (float*)d_out;

    char* ws = (char*)d_ws;
    size_t off = 0;
    auto alloc = [&](size_t bytes) -> void* {
        void* p = ws + off;
        off = (off + bytes + 255) & ~(size_t)255;
        return p;
    };
    float* stats_all = (float*)alloc(9 * 2 * DD * 4);
    int* cnt = (int*)alloc((size_t)NN * 4);  // adjacent to stats -> one memset
    float* tmp1 = (float*)alloc((size_t)NN * DD * 4);  // self h; later z1p/z1f
    float* bufA = (float*)alloc((size_t)NN * DD * 4);  // GAT agg L0/L1; GCN h1? no: agg only
    short* fbf = (short*)alloc((size_t)NN * DD * 2);   // f_in bf16; later z1u
    short* hnb = (short*)alloc((size_t)NN * DD * 2);   // GAT hn L0/L1
    short* z0u = (short*)alloc((size_t)NN * DD * 2);   // z0 -> y0 (in-place) -> y1
    short* z0p = (short*)alloc((size_t)NN * DD * 2);
    short* z0f = (short*)alloc((size_t)NN * DD * 2);
    float* rs_all = (float*)alloc((size_t)3 * NN * 4);
    float* ats_b = (float*)alloc((size_t)NN * NH * 4);
    float* atn_b = (float*)alloc((size_t)NN * NH * 4);
    short* Wt_all = (short*)alloc((size_t)14 * DD * DD * 2);  // 11 + 3 wfix slots
    float* bfix = (float*)alloc((size_t)3 * DD * 4);
    int* row_ptr = (int*)alloc((size_t)(NN + 1) * 4);
    int* fill = (int*)alloc((size_t)NN * 4);
    int* pre_b = (int*)alloc((size_t)NN * 4);
    int* bsum = (int*)alloc((size_t)SCAN_B * 4);
    int* boff = (int*)alloc((size_t)257 * 4);
    int4* ed = (int4*)alloc((size_t)NE * 32);

    auto stats = [&](int s) { return stats_all + (size_t)s * 2 * DD; };
    auto Wt = [&](int w) { return Wt_all + (size_t)w * DD * DD; };
    // stats layout: 0=GAT L0 agg, 1=GAT L1 agg, 2..4=GCN y0, 5..7=GCN y1, 8=self

    const int gE = (NE + 255) / 256;
    const int gMM = (NN + 63) / 64;
    const int gSP = (NN + 3) / 4;
    const int gCA = (NN + 255) / 256;
    const int gBF = (NN * DD / 8 + 255) / 256;

    hipMemsetAsync(stats_all, 0, 9 * 2 * DD * 4 + (size_t)NN * 4, stream);

    // CSR build
    count_kernel<<<gE, 256, 0, stream>>>(edge_row, cnt);
    scan1_kernel<<<SCAN_B, 256, 0, stream>>>(cnt, pre_b, bsum);
    scan2_kernel<<<1, 256, 0, stream>>>(bsum, boff);
    scan3_kernel<<<SCAN_B, 256, 0, stream>>>(pre_b, boff, row_ptr, fill);
    scatter_kernel<<<gE, 256, 0, stream>>>(edge_row, edge_col, vals_gat, vals_uttr, vals_past,
                                           vals_futr, fill, ed);

    tobf16_kernel<<<gBF, 256, 0, stream>>>(f_in, fbf);

    WPrepArgs wa;
    wa.src[0] = gat_Ws;
    wa.src[1] = gat_Wn;
    wa.src[2] = gat_Ws + (size_t)DD * DD;
    wa.src[3] = gat_Wn + (size_t)DD * DD;
    wa.src[4] = W_uttr;
    wa.src[5] = W_uttr + (size_t)DD * DD;  // unused (wfix), harmless
    wa.src[6] = W_past;
    wa.src[7] = W_past + (size_t)DD * DD;
    wa.src[8] = W_futr;
    wa.src[9] = W_futr + (size_t)DD * DD;
    wa.src[10] = W_self;
    wprep_kernel<<<(11 * DD * DD + 255) / 256, 256, 0, stream>>>(wa, Wt_all);

    // ---- self branch (FIRST classifier write) ----
    mfma_mm_self<<<gMM, 256, 0, stream>>>(fbf, Wt(10), b_self, stats(8), tmp1);
    cls_acc_kernel<1, true, false><<<gCA, 256, 0, stream>>>(tmp1, W_cls + (size_t)4 * DD * NCLS,
                                                            stats(8), b_cls, out);

    // ---- GAT L0 + fused gather A (also GCN L0 z) ----
    mfma_mm_pair<0><<<gMM, 256, 0, stream>>>(fbf, Wt(0), Wt(1), gat_bs, gat_bn, gat_as, gat_an,
                                             nullptr, hnb, ats_b, atn_b);
    spmm_fusedA<<<gSP, 256, 0, stream>>>(hnb, fbf, ats_b, atn_b, ed, row_ptr, bufA, z0u, z0p,
                                         z0f, rs_all);
    bn_stats_kernel<<<256, 256, 0, stream>>>(bufA, stats(0));
    // ---- GAT L1 matmul (BN on the fly) ----
    mfma_mm_pair<1><<<gMM, 256, 0, stream>>>(bufA, Wt(2), Wt(3), gat_bs + DD, gat_bn + DD,
                                             gat_as + DD, gat_an + DD, stats(0), hnb, ats_b,
                                             atn_b);

    // ---- GCN L0 matmuls (batched, in-place z0 -> y0 bf16, stats 2..4) ----
    const float* bb[3] = {b_uttr, b_past, b_futr};
    const float* Worig[3] = {W_uttr, W_past, W_futr};
    MMB m0;
    short* z0a[3] = {z0u, z0p, z0f};
    for (int br = 0; br < 3; ++br) {
        m0.A[br] = z0a[br];
        m0.W[br] = Wt(4 + br * 2);
        m0.bias[br] = bb[br];
        m0.rs[br] = rs_all + (size_t)br * NN;
        m0.stats[br] = stats(2 + br);
        m0.C[br] = z0a[br];
    }
    mfma_mm_gcn<<<dim3(gMM, 3), 256, 0, stream>>>(m0);

    // ---- wfix: fold BN(y0) into L1 weights ----
    WFixArgs wf;
    for (int br = 0; br < 3; ++br) {
        wf.W1[br] = Worig[br] + (size_t)DD * DD;
        wf.b1[br] = bb[br] + DD;
        wf.stats[br] = stats(2 + br);
    }
    wfix_kernel<<<2, 256, 0, stream>>>(wf, Wt(11), bfix);

    // ---- fused gather B: GAT-L1 agg + 3x GCN z1 ----
    short* z1u = fbf;               // fbf dead
    short* z1p = (short*)tmp1;      // tmp1 dead after self cls
    short* z1f = (short*)tmp1 + (size_t)NN * DD;
    spmm_fusedB<<<gSP, 256, 0, stream>>>(hnb, z0u, z0p, z0f, ats_b, atn_b, ed, row_ptr, bufA,
                                         z1u, z1p, z1f);
    bn_stats_kernel<<<256, 256, 0, stream>>>(bufA, stats(1));
    cls_acc_kernel<1, false, false><<<gCA, 256, 0, stream>>>(bufA, W_cls, stats(1), b_cls, out);

    // ---- GCN L1 matmuls (batched, z1 -> y1 bf16 into z0 slots, stats 5..7) ----
    MMB m1;
    short* z1a[3] = {z1u, z1p, z1f};
    for (int br = 0; br < 3; ++br) {
        m1.A[br] = z1a[br];
        m1.W[br] = Wt(11 + br);
        m1.bias[br] = bfix + (size_t)br * DD;
        m1.rs[br] = rs_all + (size_t)br * NN;
        m1.stats[br] = stats(5 + br);
        m1.C[br] = z0a[br];
    }
    mfma_mm_gcn<<<dim3(gMM, 3), 256, 0, stream>>>(m1);

    // ---- GCN classifiers (bf16 input, BN only) ----
    for (int br = 0; br < 3; ++br)
        cls_acc_kernel<1, false, true><<<gCA, 256, 0, stream>>>(
            z0a[br], W_cls + (size_t)(DD + DD * br) * NCLS, stats(5 + br), b_cls, out);
}